// Round 1
// baseline (4693.800 us; speedup 1.0000x reference)
//
#include <hip/hip_runtime.h>

#define CH 128
#define NH 4
// head dim = 32, 1/sqrt(32)
#define INV_SQRT_D 0.17677669529663687f

// ---- monotone float<->uint mapping so atomicMax(uint) == float max ----
// init value 0 decodes below every real float's encoding (all real encodings >= 0x007FFFFF)
__device__ __forceinline__ unsigned f2mono(float f) {
    unsigned b = __float_as_uint(f);
    return (b & 0x80000000u) ? ~b : (b | 0x80000000u);
}
__device__ __forceinline__ float mono2f(unsigned u) {
    unsigned b = (u & 0x80000000u) ? (u ^ 0x80000000u) : ~u;
    return __uint_as_float(b);
}

// ======================= QKV projection: y = x @ W^T + b =======================
// grid.y = 0..5 -> {A,B} x {Q,K,V}; 64 rows per block; W^T staged in LDS.
__global__ __launch_bounds__(256) void qkv_gemm(
    const float* __restrict__ xA, const float* __restrict__ xB,
    const float* __restrict__ Wq, const float* __restrict__ bq,
    const float* __restrict__ Wk, const float* __restrict__ bk,
    const float* __restrict__ Wv, const float* __restrict__ bv,
    float* __restrict__ ws, int n)
{
    __shared__ float Wt[CH][CH];   // Wt[k][j] = W[j][k]
    __shared__ float xs[64][CH];

    const int tid = threadIdx.x;
    const int which = blockIdx.y;
    const float* x = (which < 3) ? xA : xB;
    const int p = which % 3;
    const float* W = (p == 0) ? Wq : (p == 1) ? Wk : Wv;
    const float* b = (p == 0) ? bq : (p == 1) ? bk : bv;
    float* y = ws + (size_t)which * n * CH;
    const int row0 = blockIdx.x * 64;

    // stage W transposed (one-time per block; write conflicts are amortized)
    for (int i = tid; i < CH * CH / 4; i += 256) {
        int g = i * 4;
        int j = g >> 7, k = g & 127;
        float4 w = *(const float4*)(W + g);
        Wt[k + 0][j] = w.x; Wt[k + 1][j] = w.y; Wt[k + 2][j] = w.z; Wt[k + 3][j] = w.w;
    }
    // stage x rows (zero-fill OOB)
    for (int i = tid; i < 64 * CH / 4; i += 256) {
        int g = i * 4;
        int r = g >> 7, c = g & 127;
        float4 v = make_float4(0.f, 0.f, 0.f, 0.f);
        if (row0 + r < n) v = *(const float4*)(x + (size_t)(row0 + r) * CH + c);
        *(float4*)&xs[r][c] = v;
    }
    __syncthreads();

    const int c4 = (tid & 31) * 4;       // 4 output cols
    const int rg = (tid >> 5) * 2;       // 2 rows per thread per pass
    const float4 bb = *(const float4*)(b + c4);

    for (int pass = 0; pass < 4; ++pass) {
        const int r0 = pass * 16 + rg;
        float4 a0 = make_float4(0.f, 0.f, 0.f, 0.f);
        float4 a1 = make_float4(0.f, 0.f, 0.f, 0.f);
        #pragma unroll 8
        for (int k = 0; k < CH; ++k) {
            float4 w = *(const float4*)&Wt[k][c4];
            float x0 = xs[r0][k], x1 = xs[r0 + 1][k];
            a0.x += w.x * x0; a0.y += w.y * x0; a0.z += w.z * x0; a0.w += w.w * x0;
            a1.x += w.x * x1; a1.y += w.y * x1; a1.z += w.z * x1; a1.w += w.w * x1;
        }
        const int row = row0 + r0;
        if (row < n) {
            float4 o; o.x = a0.x + bb.x; o.y = a0.y + bb.y; o.z = a0.z + bb.z; o.w = a0.w + bb.w;
            *(float4*)(y + (size_t)row * CH + c4) = o;
        }
        if (row + 1 < n) {
            float4 o; o.x = a1.x + bb.x; o.y = a1.y + bb.y; o.z = a1.z + bb.z; o.w = a1.w + bb.w;
            *(float4*)(y + (size_t)(row + 1) * CH + c4) = o;
        }
    }
}

// ======================= Pass A: per-edge scores + segment max =======================
// 32 lanes per edge (8 edges / 256-thread block); float4 per lane over the 128-ch row.
__global__ __launch_bounds__(256) void edge_scores(
    const float* __restrict__ Qdst, const float* __restrict__ Ksrc,
    const int* __restrict__ ei,          // [2, nE]
    const float* __restrict__ sb, const float* __restrict__ bias,
    float* __restrict__ scores,          // [nE, NH]
    unsigned* __restrict__ mdst,         // [n, NH] monotone-encoded max
    int nE)
{
    const int e = blockIdx.x * 8 + (threadIdx.x >> 5);
    if (e >= nE) return;
    const int l = threadIdx.x & 31;
    const int src = ei[e];
    const int dst = ei[nE + e];

    float4 q = *(const float4*)(Qdst + (size_t)dst * CH + l * 4);
    float4 k = *(const float4*)(Ksrc + (size_t)src * CH + l * 4);
    float part = q.x * k.x + q.y * k.y + q.z * k.z + q.w * k.w;
    // reduce within 8-lane head groups (head h = l>>3 owns channels [32h,32h+32))
    part += __shfl_xor(part, 1);
    part += __shfl_xor(part, 2);
    part += __shfl_xor(part, 4);
    if ((l & 7) == 0) {
        const int h = l >> 3;
        float s = part * INV_SQRT_D + sb[e] + bias[0];
        scores[(size_t)e * NH + h] = s;
        atomicMax(&mdst[(size_t)dst * NH + h], f2mono(s));
    }
}

// ======================= Pass B: exp, denom, un-normalized V scatter =======================
__global__ __launch_bounds__(256) void edge_message(
    const float* __restrict__ Vsrc,
    const int* __restrict__ ei,
    const float* __restrict__ scores, const unsigned* __restrict__ mdst,
    float* __restrict__ denom,           // [n, NH]
    float* __restrict__ accum,           // [n, CH]  (lives in d_out)
    int nE)
{
    const int e = blockIdx.x * 8 + (threadIdx.x >> 5);
    if (e >= nE) return;
    const int l = threadIdx.x & 31;
    const int src = ei[e];
    const int dst = ei[nE + e];
    const int h = l >> 3;

    float s = scores[(size_t)e * NH + h];
    float m = mono2f(mdst[(size_t)dst * NH + h]);
    float ex = __expf(s - m);
    if ((l & 7) == 0) atomicAdd(&denom[(size_t)dst * NH + h], ex);

    float4 v = *(const float4*)(Vsrc + (size_t)src * CH + l * 4);
    float* ap = accum + (size_t)dst * CH + l * 4;
    atomicAdd(ap + 0, v.x * ex);
    atomicAdd(ap + 1, v.y * ex);
    atomicAdd(ap + 2, v.z * ex);
    atomicAdd(ap + 3, v.w * ex);
}

// ======================= Finalize: normalize + residual + LayerNorm (in place) =======================
// One 64-lane wave per node, 2 channels per lane. NOTE: the reference's degree term is a
// per-row constant added before LN -> it cancels exactly in LN's mean subtraction; skipped.
__global__ __launch_bounds__(256) void finalize_ln(
    const float* __restrict__ x, const float* __restrict__ accum,
    const float* __restrict__ denom,
    const float* __restrict__ gamma, const float* __restrict__ beta,
    float* __restrict__ out, int n)
{
    const int node = blockIdx.x * 4 + (threadIdx.x >> 6);
    if (node >= n) return;
    const int l = threadIdx.x & 63;
    const int h = l >> 4;                 // channels 2l,2l+1 -> head (2l)/32

    float2 a = *(const float2*)(accum + (size_t)node * CH + l * 2);
    float d = denom[(size_t)node * NH + h];
    float inv = (d > 0.f) ? 1.f / d : 0.f;   // empty dst segment -> message 0
    float2 xv = *(const float2*)(x + (size_t)node * CH + l * 2);

    float v0 = a.x * inv + xv.x;
    float v1 = a.y * inv + xv.y;

    float sum = v0 + v1;
    #pragma unroll
    for (int off = 32; off; off >>= 1) sum += __shfl_xor(sum, off);
    const float mean = sum * (1.f / 128.f);
    const float c0 = v0 - mean, c1 = v1 - mean;
    float vs = c0 * c0 + c1 * c1;
    #pragma unroll
    for (int off = 32; off; off >>= 1) vs += __shfl_xor(vs, off);
    const float rstd = rsqrtf(vs * (1.f / 128.f) + 1e-5f);

    float2 g = *(const float2*)(gamma + l * 2);
    float2 bt = *(const float2*)(beta + l * 2);
    float2 o;
    o.x = c0 * rstd * g.x + bt.x;
    o.y = c1 * rstd * g.y + bt.y;
    *(float2*)(out + (size_t)node * CH + l * 2) = o;
}

extern "C" void kernel_launch(void* const* d_in, const int* in_sizes, int n_in,
                              void* d_out, int out_size, void* d_ws, size_t ws_size,
                              hipStream_t stream)
{
    const float* xA     = (const float*)d_in[0];
    const float* xB     = (const float*)d_in[1];
    const float* Wq     = (const float*)d_in[2];
    const float* bq     = (const float*)d_in[3];
    const float* Wk     = (const float*)d_in[4];
    const float* bk     = (const float*)d_in[5];
    const float* Wv     = (const float*)d_in[6];
    const float* bv     = (const float*)d_in[7];
    const float* gamma  = (const float*)d_in[8];
    const float* beta   = (const float*)d_in[9];
    const float* biasAB = (const float*)d_in[10];
    const float* biasBA = (const float*)d_in[11];
    const float* sbAB   = (const float*)d_in[12];
    const float* sbBA   = (const float*)d_in[13];
    const int*   eiAB   = (const int*)d_in[14];
    const int*   eiBA   = (const int*)d_in[15];

    const int n  = in_sizes[0] / CH;     // 100000
    const int nE = in_sizes[12];         // 1000000
    const size_t NC = (size_t)n * CH;

    // workspace layout (floats): Q_A K_A V_A Q_B K_B V_B | sc_AB sc_BA | m_B m_A den_B den_A
    float* ws   = (float*)d_ws;
    float* Q_A  = ws + 0 * NC;
    float* K_A  = ws + 1 * NC;
    float* V_A  = ws + 2 * NC;
    float* Q_B  = ws + 3 * NC;
    float* K_B  = ws + 4 * NC;
    float* V_B  = ws + 5 * NC;
    float* sc_AB = ws + 6 * NC;
    float* sc_BA = sc_AB + (size_t)nE * NH;
    unsigned* m_B = (unsigned*)(sc_BA + (size_t)nE * NH);
    unsigned* m_A = m_B + (size_t)n * NH;
    float* den_B  = (float*)(m_A + (size_t)n * NH);
    float* den_A  = den_B + (size_t)n * NH;

    float* out   = (float*)d_out;
    float* acc_A = out;            // accumulate messages for out_A directly in d_out
    float* acc_B = out + NC;

    // zero: m_B,m_A,den_B,den_A (contiguous) and the output accumulators
    hipMemsetAsync(m_B, 0, (size_t)n * NH * 4 * sizeof(float), stream);
    hipMemsetAsync(out, 0, 2 * NC * sizeof(float), stream);

    dim3 gemm_grid((n + 63) / 64, 6);
    qkv_gemm<<<gemm_grid, 256, 0, stream>>>(xA, xB, Wq, bq, Wk, bk, Wv, bv, ws, n);

    const int eb = (nE + 7) / 8;
    edge_scores<<<eb, 256, 0, stream>>>(Q_B, K_A, eiAB, sbAB, biasAB, sc_AB, m_B, nE);
    edge_scores<<<eb, 256, 0, stream>>>(Q_A, K_B, eiBA, sbBA, biasBA, sc_BA, m_A, nE);
    edge_message<<<eb, 256, 0, stream>>>(V_A, eiAB, sc_AB, m_B, den_B, acc_B, nE);
    edge_message<<<eb, 256, 0, stream>>>(V_B, eiBA, sc_BA, m_A, den_A, acc_A, nE);

    const int fb = (n + 3) / 4;
    finalize_ln<<<fb, 256, 0, stream>>>(xA, acc_A, den_A, gamma, beta, out, n);
    finalize_ln<<<fb, 256, 0, stream>>>(xB, acc_B, den_B, gamma, beta, out + NC, n);
}

// Round 2
// 1384.557 us; speedup vs baseline: 3.3901x; 3.3901x over previous
//
#include <hip/hip_runtime.h>

#define CH 128
#define NH 4
// head dim = 32, 1/sqrt(32)
#define INV_SQRT_D 0.17677669529663687f
#define SCAN_BLK 1024

// ======================= QKV projection: y = x @ W^T + b =======================
// grid.y = 0..5 -> {A,B} x {Q,K,V}; 64 rows per block; W^T staged in LDS.
__global__ __launch_bounds__(256) void qkv_gemm(
    const float* __restrict__ xA, const float* __restrict__ xB,
    const float* __restrict__ Wq, const float* __restrict__ bq,
    const float* __restrict__ Wk, const float* __restrict__ bk,
    const float* __restrict__ Wv, const float* __restrict__ bv,
    float* __restrict__ ws, int n)
{
    __shared__ float Wt[CH][CH];   // Wt[k][j] = W[j][k]
    __shared__ float xs[64][CH];

    const int tid = threadIdx.x;
    const int which = blockIdx.y;
    const float* x = (which < 3) ? xA : xB;
    const int p = which % 3;
    const float* W = (p == 0) ? Wq : (p == 1) ? Wk : Wv;
    const float* b = (p == 0) ? bq : (p == 1) ? bk : bv;
    float* y = ws + (size_t)which * n * CH;
    const int row0 = blockIdx.x * 64;

    for (int i = tid; i < CH * CH / 4; i += 256) {
        int g = i * 4;
        int j = g >> 7, k = g & 127;
        float4 w = *(const float4*)(W + g);
        Wt[k + 0][j] = w.x; Wt[k + 1][j] = w.y; Wt[k + 2][j] = w.z; Wt[k + 3][j] = w.w;
    }
    for (int i = tid; i < 64 * CH / 4; i += 256) {
        int g = i * 4;
        int r = g >> 7, c = g & 127;
        float4 v = make_float4(0.f, 0.f, 0.f, 0.f);
        if (row0 + r < n) v = *(const float4*)(x + (size_t)(row0 + r) * CH + c);
        *(float4*)&xs[r][c] = v;
    }
    __syncthreads();

    const int c4 = (tid & 31) * 4;
    const int rg = (tid >> 5) * 2;
    const float4 bb = *(const float4*)(b + c4);

    for (int pass = 0; pass < 4; ++pass) {
        const int r0 = pass * 16 + rg;
        float4 a0 = make_float4(0.f, 0.f, 0.f, 0.f);
        float4 a1 = make_float4(0.f, 0.f, 0.f, 0.f);
        #pragma unroll 8
        for (int k = 0; k < CH; ++k) {
            float4 w = *(const float4*)&Wt[k][c4];
            float x0 = xs[r0][k], x1 = xs[r0 + 1][k];
            a0.x += w.x * x0; a0.y += w.y * x0; a0.z += w.z * x0; a0.w += w.w * x0;
            a1.x += w.x * x1; a1.y += w.y * x1; a1.z += w.z * x1; a1.w += w.w * x1;
        }
        const int row = row0 + r0;
        if (row < n) {
            float4 o; o.x = a0.x + bb.x; o.y = a0.y + bb.y; o.z = a0.z + bb.z; o.w = a0.w + bb.w;
            *(float4*)(y + (size_t)row * CH + c4) = o;
        }
        if (row + 1 < n) {
            float4 o; o.x = a1.x + bb.x; o.y = a1.y + bb.y; o.z = a1.z + bb.z; o.w = a1.w + bb.w;
            *(float4*)(y + (size_t)(row + 1) * CH + c4) = o;
        }
    }
}

// ======================= CSR build: histogram -> scan -> fill =======================
__global__ __launch_bounds__(256) void deg_hist(const int* __restrict__ ei, int* __restrict__ deg, int nE)
{
    int e = blockIdx.x * 256 + threadIdx.x;
    if (e < nE) atomicAdd(&deg[ei[nE + e]], 1);
}

// per-block (1024 elems) exclusive scan; block sums out
__global__ __launch_bounds__(256) void scan_local(const int* __restrict__ deg, int* __restrict__ offs,
                                                  int* __restrict__ bsums, int n)
{
    __shared__ int s[256];
    const int t = threadIdx.x;
    const int base = blockIdx.x * SCAN_BLK + t * 4;
    int v0 = 0, v1 = 0, v2 = 0, v3 = 0;
    if (base + 3 < n) {
        int4 q = *(const int4*)(deg + base);
        v0 = q.x; v1 = q.y; v2 = q.z; v3 = q.w;
    } else {
        if (base + 0 < n) v0 = deg[base + 0];
        if (base + 1 < n) v1 = deg[base + 1];
        if (base + 2 < n) v2 = deg[base + 2];
    }
    const int tsum = v0 + v1 + v2 + v3;
    s[t] = tsum;
    __syncthreads();
    for (int off = 1; off < 256; off <<= 1) {
        int add = (t >= off) ? s[t - off] : 0;
        __syncthreads();
        s[t] += add;
        __syncthreads();
    }
    const int excl = s[t] - tsum;
    if (base + 0 < n) offs[base + 0] = excl;
    if (base + 1 < n) offs[base + 1] = excl + v0;
    if (base + 2 < n) offs[base + 2] = excl + v0 + v1;
    if (base + 3 < n) offs[base + 3] = excl + v0 + v1 + v2;
    if (t == 255) bsums[blockIdx.x] = s[255];
}

// exclusive scan of block sums (nb <= 256), single block
__global__ __launch_bounds__(256) void scan_bsums(int* __restrict__ bsums, int nb)
{
    __shared__ int s[256];
    const int t = threadIdx.x;
    int v = (t < nb) ? bsums[t] : 0;
    s[t] = v;
    __syncthreads();
    for (int off = 1; off < 256; off <<= 1) {
        int add = (t >= off) ? s[t - off] : 0;
        __syncthreads();
        s[t] += add;
        __syncthreads();
    }
    if (t < nb) bsums[t] = s[t] - v;
}

__global__ __launch_bounds__(256) void add_bsums(int* __restrict__ offs, const int* __restrict__ bsums, int n)
{
    int i = blockIdx.x * 256 + threadIdx.x;
    if (i < n) offs[i] += bsums[i >> 10];   // SCAN_BLK = 1024
}

// scatter edges into dst-sorted order; pre-gather src index and spatial bias
__global__ __launch_bounds__(256) void csr_fill(const int* __restrict__ ei, const float* __restrict__ sb,
                                                const int* __restrict__ offs, int* __restrict__ cursor,
                                                int* __restrict__ srcs, float* __restrict__ sbs, int nE)
{
    int e = blockIdx.x * 256 + threadIdx.x;
    if (e >= nE) return;
    const int dst = ei[nE + e];
    const int pos = offs[dst] + atomicAdd(&cursor[dst], 1);
    srcs[pos] = ei[e];
    sbs[pos] = sb[e];
}

// ======================= Fused per-node attention + residual + LayerNorm =======================
// One 64-lane wave per dst node; 2 channels/lane; head h = lane>>4 (16 lanes per head).
// Online softmax (running max/denom/accum) -> no score storage, no atomics, no second pass.
// NOTE: reference's degree term is a per-row constant before LN -> cancels in mean subtraction.
__global__ __launch_bounds__(256) void attn_node(
    const float* __restrict__ Q, const float* __restrict__ K, const float* __restrict__ V,
    const float* __restrict__ x,
    const int* __restrict__ offs, const int* __restrict__ deg,
    const int* __restrict__ srcs, const float* __restrict__ sbs,
    const float* __restrict__ bias,
    const float* __restrict__ gamma, const float* __restrict__ beta,
    float* __restrict__ out, int n)
{
    const int node = blockIdx.x * 4 + (threadIdx.x >> 6);
    if (node >= n) return;
    const int l = threadIdx.x & 63;

    float2 q = *(const float2*)(Q + (size_t)node * CH + l * 2);
    q.x *= INV_SQRT_D; q.y *= INV_SQRT_D;
    const float bia = bias[0];
    const int beg = offs[node];
    const int d = deg[node];

    float m = -3.0e38f, den = 0.f, a0 = 0.f, a1 = 0.f;

    // software-pipelined K/V gather: fetch edge i+1's rows while reducing edge i
    float2 kc, vc;
    if (d > 0) {
        const int s0 = srcs[beg];
        kc = *(const float2*)(K + (size_t)s0 * CH + l * 2);
        vc = *(const float2*)(V + (size_t)s0 * CH + l * 2);
    }
    for (int i = 0; i < d; ++i) {
        const float sbv = sbs[beg + i];
        const float2 k = kc, v = vc;
        if (i + 1 < d) {
            const int s1 = srcs[beg + i + 1];
            kc = *(const float2*)(K + (size_t)s1 * CH + l * 2);
            vc = *(const float2*)(V + (size_t)s1 * CH + l * 2);
        }
        float part = q.x * k.x + q.y * k.y;
        part += __shfl_xor(part, 1);
        part += __shfl_xor(part, 2);
        part += __shfl_xor(part, 4);
        part += __shfl_xor(part, 8);      // all 16 lanes of the head hold the dot
        const float s = part + sbv + bia;
        const float mn = fmaxf(m, s);
        const float scale = __expf(m - mn);
        const float ex = __expf(s - mn);
        den = den * scale + ex;
        a0 = a0 * scale + ex * v.x;
        a1 = a1 * scale + ex * v.y;
        m = mn;
    }

    const float inv = (den > 0.f) ? 1.f / den : 0.f;   // empty segment -> message 0
    const float2 xv = *(const float2*)(x + (size_t)node * CH + l * 2);
    float v0 = a0 * inv + xv.x;
    float v1 = a1 * inv + xv.y;

    float sum = v0 + v1;
    #pragma unroll
    for (int off = 32; off; off >>= 1) sum += __shfl_xor(sum, off);
    const float mean = sum * (1.f / 128.f);
    const float c0 = v0 - mean, c1 = v1 - mean;
    float vs = c0 * c0 + c1 * c1;
    #pragma unroll
    for (int off = 32; off; off >>= 1) vs += __shfl_xor(vs, off);
    const float rstd = rsqrtf(vs * (1.f / 128.f) + 1e-5f);

    const float2 g = *(const float2*)(gamma + l * 2);
    const float2 bt = *(const float2*)(beta + l * 2);
    float2 o;
    o.x = c0 * rstd * g.x + bt.x;
    o.y = c1 * rstd * g.y + bt.y;
    *(float2*)(out + (size_t)node * CH + l * 2) = o;
}

extern "C" void kernel_launch(void* const* d_in, const int* in_sizes, int n_in,
                              void* d_out, int out_size, void* d_ws, size_t ws_size,
                              hipStream_t stream)
{
    const float* xA     = (const float*)d_in[0];
    const float* xB     = (const float*)d_in[1];
    const float* Wq     = (const float*)d_in[2];
    const float* bq     = (const float*)d_in[3];
    const float* Wk     = (const float*)d_in[4];
    const float* bk     = (const float*)d_in[5];
    const float* Wv     = (const float*)d_in[6];
    const float* bv     = (const float*)d_in[7];
    const float* gamma  = (const float*)d_in[8];
    const float* beta   = (const float*)d_in[9];
    const float* biasAB = (const float*)d_in[10];
    const float* biasBA = (const float*)d_in[11];
    const float* sbAB   = (const float*)d_in[12];
    const float* sbBA   = (const float*)d_in[13];
    const int*   eiAB   = (const int*)d_in[14];
    const int*   eiBA   = (const int*)d_in[15];

    const int n  = in_sizes[0] / CH;     // 100000
    const int nE = in_sizes[12];         // 1000000
    const size_t NC = (size_t)n * CH;

    // workspace layout:
    //   [6*NC floats] QKV for A then B
    //   [nE int] srcsAB  [nE f32] sbsAB  [nE int] srcsBA  [nE f32] sbsBA
    //   [n] offsAB [n] offsBA [n] degAB [n] degBA [n] curAB [n] curBA  (deg..cur zeroed)
    //   [256] bsumsAB [256] bsumsBA
    float* ws    = (float*)d_ws;
    float* Q_A   = ws + 0 * NC;
    float* K_A   = ws + 1 * NC;
    float* V_A   = ws + 2 * NC;
    float* Q_B   = ws + 3 * NC;
    float* K_B   = ws + 4 * NC;
    float* V_B   = ws + 5 * NC;
    int*   srcsAB = (int*)(ws + 6 * NC);
    float* sbsAB  = (float*)(srcsAB + nE);
    int*   srcsBA = (int*)(sbsAB + nE);
    float* sbsBA  = (float*)(srcsBA + nE);
    int*   offsAB = (int*)(sbsBA + nE);
    int*   offsBA = offsAB + n;
    int*   degAB  = offsBA + n;
    int*   degBA  = degAB + n;
    int*   curAB  = degBA + n;
    int*   curBA  = curAB + n;
    int*   bsumsAB = curBA + n;
    int*   bsumsBA = bsumsAB + 256;

    float* out   = (float*)d_out;

    hipMemsetAsync(degAB, 0, (size_t)4 * n * sizeof(int), stream);  // degAB,degBA,curAB,curBA

    dim3 gemm_grid((n + 63) / 64, 6);
    qkv_gemm<<<gemm_grid, 256, 0, stream>>>(xA, xB, Wq, bq, Wk, bk, Wv, bv, ws, n);

    const int ebl = (nE + 255) / 256;
    deg_hist<<<ebl, 256, 0, stream>>>(eiAB, degAB, nE);
    deg_hist<<<ebl, 256, 0, stream>>>(eiBA, degBA, nE);

    const int nb = (n + SCAN_BLK - 1) / SCAN_BLK;   // 98 <= 256
    scan_local<<<nb, 256, 0, stream>>>(degAB, offsAB, bsumsAB, n);
    scan_local<<<nb, 256, 0, stream>>>(degBA, offsBA, bsumsBA, n);
    scan_bsums<<<1, 256, 0, stream>>>(bsumsAB, nb);
    scan_bsums<<<1, 256, 0, stream>>>(bsumsBA, nb);
    add_bsums<<<(n + 255) / 256, 256, 0, stream>>>(offsAB, bsumsAB, n);
    add_bsums<<<(n + 255) / 256, 256, 0, stream>>>(offsBA, bsumsBA, n);

    csr_fill<<<ebl, 256, 0, stream>>>(eiAB, sbAB, offsAB, curAB, srcsAB, sbsAB, nE);
    csr_fill<<<ebl, 256, 0, stream>>>(eiBA, sbBA, offsBA, curBA, srcsBA, sbsBA, nE);

    // out_A <- direction BA (dst type A), out_B <- direction AB (dst type B)
    const int abl = (n + 3) / 4;
    attn_node<<<abl, 256, 0, stream>>>(Q_A, K_B, V_B, xA, offsBA, degBA, srcsBA, sbsBA,
                                       biasBA, gamma, beta, out, n);
    attn_node<<<abl, 256, 0, stream>>>(Q_B, K_A, V_A, xB, offsAB, degAB, srcsAB, sbsAB,
                                       biasAB, gamma, beta, out + NC, n);
}

// Round 3
// 779.672 us; speedup vs baseline: 6.0202x; 1.7758x over previous
//
#include <hip/hip_runtime.h>

#define CH 128
// head dim = 32, 1/sqrt(32)
#define INV_SQRT_D 0.17677669529663687f
#define SCAN_BLK 1024

typedef __attribute__((ext_vector_type(8))) short bf16x8;
typedef __attribute__((ext_vector_type(4))) float f32x4;

__device__ __forceinline__ unsigned short f2bf(float f) {
    unsigned u = __float_as_uint(f);
    return (unsigned short)((u + 0x7FFFu + ((u >> 16) & 1u)) >> 16);  // RNE
}
__device__ __forceinline__ float bf2f(unsigned short s) {
    return __uint_as_float(((unsigned)s) << 16);
}

// ======================= weight fp32 -> bf16 (one-time tiny pass) =======================
__global__ __launch_bounds__(256) void wcvt(const float* __restrict__ Wq, const float* __restrict__ Wk,
                                            const float* __restrict__ Wv, unsigned short* __restrict__ out)
{
    const int i = blockIdx.x * 256 + threadIdx.x;      // 0 .. 3*16384-1
    if (i >= 3 * CH * CH) return;
    const float* W = (i < CH * CH) ? Wq : (i < 2 * CH * CH) ? Wk : Wv;
    out[i] = f2bf(W[i & (CH * CH - 1)]);
}

// ======================= Fused QKV projection via bf16 MFMA =======================
// grid = ((n+63)/64, 2 types); 4 waves/block, wave owns 16 rows x 128 cols x {Q,K,V}.
// Fragment layout (mfma_f32_16x16x32_bf16): A: row=l&15, k=(l>>4)*8+j ; B: col=l&15, same k;
// C/D: col=l&15, row=(l>>4)*4+reg  [m89-verified]. No LDS -> no conflicts, no LDS occupancy cap.
__global__ __launch_bounds__(256) void qkv_mfma(
    const float* __restrict__ xA, const float* __restrict__ xB,
    const unsigned short* __restrict__ Wb,   // [3][128][128] bf16 (q,k,v)
    const float* __restrict__ bq, const float* __restrict__ bk, const float* __restrict__ bv,
    float* __restrict__ Qf,                  // [2][n][128] fp32
    unsigned short* __restrict__ Kb,         // [2][n][128] bf16
    unsigned short* __restrict__ Vb,         // [2][n][128] bf16
    int n)
{
    const int type = blockIdx.y;
    const float* x = type ? xB : xA;
    float*          Qo = Qf + (size_t)type * n * CH;
    unsigned short* Ko = Kb + (size_t)type * n * CH;
    unsigned short* Vo = Vb + (size_t)type * n * CH;

    const int w  = threadIdx.x >> 6;
    const int l  = threadIdx.x & 63;
    const int lr = l & 15;      // A-row / B-col within tile
    const int lg = l >> 4;      // k-group
    const int arow = blockIdx.x * 64 + w * 16 + lr;

    f32x4 acc[3][8];
    #pragma unroll
    for (int p = 0; p < 3; ++p)
        #pragma unroll
        for (int ct = 0; ct < 8; ++ct)
            acc[p][ct] = (f32x4){0.f, 0.f, 0.f, 0.f};

    #pragma unroll
    for (int kt = 0; kt < 4; ++kt) {
        float xv[8];
        if (arow < n) {
            const float* xp = x + (size_t)arow * CH + kt * 32 + lg * 8;
            const float4 x0 = *(const float4*)xp;
            const float4 x1 = *(const float4*)(xp + 4);
            xv[0] = x0.x; xv[1] = x0.y; xv[2] = x0.z; xv[3] = x0.w;
            xv[4] = x1.x; xv[5] = x1.y; xv[6] = x1.z; xv[7] = x1.w;
        } else {
            #pragma unroll
            for (int j = 0; j < 8; ++j) xv[j] = 0.f;
        }
        bf16x8 a;
        #pragma unroll
        for (int j = 0; j < 8; ++j) a[j] = (short)f2bf(xv[j]);

        #pragma unroll
        for (int p = 0; p < 3; ++p) {
            #pragma unroll
            for (int ct = 0; ct < 8; ++ct) {
                const unsigned short* wp = Wb + ((size_t)p << 14) + (ct * 16 + lr) * CH + kt * 32 + lg * 8;
                const bf16x8 b = *(const bf16x8*)wp;
                acc[p][ct] = __builtin_amdgcn_mfma_f32_16x16x32_bf16(a, b, acc[p][ct], 0, 0, 0);
            }
        }
    }

    // epilogue: bias add; Q fp32, K/V bf16
    const int orow0 = blockIdx.x * 64 + w * 16 + lg * 4;
    #pragma unroll
    for (int ct = 0; ct < 8; ++ct) {
        const int col = ct * 16 + lr;
        const float bbq = bq[col], bbk = bk[col], bbv = bv[col];
        #pragma unroll
        for (int r = 0; r < 4; ++r) {
            const int orow = orow0 + r;
            if (orow < n) {
                const size_t off = (size_t)orow * CH + col;
                Qo[off] = acc[0][ct][r] + bbq;
                Ko[off] = f2bf(acc[1][ct][r] + bbk);
                Vo[off] = f2bf(acc[2][ct][r] + bbv);
            }
        }
    }
}

// ======================= CSR build: histogram -> scan -> fill =======================
__global__ __launch_bounds__(256) void deg_hist(const int* __restrict__ ei, int* __restrict__ deg, int nE)
{
    int e = blockIdx.x * 256 + threadIdx.x;
    if (e < nE) atomicAdd(&deg[ei[nE + e]], 1);
}

__global__ __launch_bounds__(256) void scan_local(const int* __restrict__ deg, int* __restrict__ offs,
                                                  int* __restrict__ bsums, int n)
{
    __shared__ int s[256];
    const int t = threadIdx.x;
    const int base = blockIdx.x * SCAN_BLK + t * 4;
    int v0 = 0, v1 = 0, v2 = 0, v3 = 0;
    if (base + 3 < n) {
        int4 q = *(const int4*)(deg + base);
        v0 = q.x; v1 = q.y; v2 = q.z; v3 = q.w;
    } else {
        if (base + 0 < n) v0 = deg[base + 0];
        if (base + 1 < n) v1 = deg[base + 1];
        if (base + 2 < n) v2 = deg[base + 2];
    }
    const int tsum = v0 + v1 + v2 + v3;
    s[t] = tsum;
    __syncthreads();
    for (int off = 1; off < 256; off <<= 1) {
        int add = (t >= off) ? s[t - off] : 0;
        __syncthreads();
        s[t] += add;
        __syncthreads();
    }
    const int excl = s[t] - tsum;
    if (base + 0 < n) offs[base + 0] = excl;
    if (base + 1 < n) offs[base + 1] = excl + v0;
    if (base + 2 < n) offs[base + 2] = excl + v0 + v1;
    if (base + 3 < n) offs[base + 3] = excl + v0 + v1 + v2;
    if (t == 255) bsums[blockIdx.x] = s[255];
}

__global__ __launch_bounds__(256) void scan_bsums(int* __restrict__ bsums, int nb)
{
    __shared__ int s[256];
    const int t = threadIdx.x;
    int v = (t < nb) ? bsums[t] : 0;
    s[t] = v;
    __syncthreads();
    for (int off = 1; off < 256; off <<= 1) {
        int add = (t >= off) ? s[t - off] : 0;
        __syncthreads();
        s[t] += add;
        __syncthreads();
    }
    if (t < nb) bsums[t] = s[t] - v;
}

__global__ __launch_bounds__(256) void add_bsums(int* __restrict__ offs, const int* __restrict__ bsums, int n)
{
    int i = blockIdx.x * 256 + threadIdx.x;
    if (i < n) offs[i] += bsums[i >> 10];   // SCAN_BLK = 1024
}

__global__ __launch_bounds__(256) void csr_fill(const int* __restrict__ ei, const float* __restrict__ sb,
                                                const int* __restrict__ offs, int* __restrict__ cursor,
                                                int* __restrict__ srcs, float* __restrict__ sbs, int nE)
{
    int e = blockIdx.x * 256 + threadIdx.x;
    if (e >= nE) return;
    const int dst = ei[nE + e];
    const int pos = offs[dst] + atomicAdd(&cursor[dst], 1);
    srcs[pos] = ei[e];
    sbs[pos] = sb[e];
}

// ======================= Fused per-node attention + residual + LayerNorm =======================
// One wave per dst node; 2 channels/lane; head h = lane>>4. Online softmax; K/V gathered as bf16.
// Reference's degree term is a per-row constant before LN -> cancels in mean subtraction.
__global__ __launch_bounds__(256) void attn_node(
    const float* __restrict__ Q, const unsigned short* __restrict__ K, const unsigned short* __restrict__ V,
    const float* __restrict__ x,
    const int* __restrict__ offs, const int* __restrict__ deg,
    const int* __restrict__ srcs, const float* __restrict__ sbs,
    const float* __restrict__ bias,
    const float* __restrict__ gamma, const float* __restrict__ beta,
    float* __restrict__ out, int n)
{
    const int node = blockIdx.x * 4 + (threadIdx.x >> 6);
    if (node >= n) return;
    const int l = threadIdx.x & 63;

    float2 q = *(const float2*)(Q + (size_t)node * CH + l * 2);
    q.x *= INV_SQRT_D; q.y *= INV_SQRT_D;
    const float bia = bias[0];
    const int beg = offs[node];
    const int d = deg[node];

    float m = -3.0e38f, den = 0.f, a0 = 0.f, a1 = 0.f;

    unsigned kc = 0, vc = 0;
    if (d > 0) {
        const int s0 = srcs[beg];
        kc = *(const unsigned*)(K + (size_t)s0 * CH + l * 2);
        vc = *(const unsigned*)(V + (size_t)s0 * CH + l * 2);
    }
    for (int i = 0; i < d; ++i) {
        const float sbv = sbs[beg + i];
        const float kx = bf2f((unsigned short)kc), ky = bf2f((unsigned short)(kc >> 16));
        const float vx = bf2f((unsigned short)vc), vy = bf2f((unsigned short)(vc >> 16));
        if (i + 1 < d) {
            const int s1 = srcs[beg + i + 1];
            kc = *(const unsigned*)(K + (size_t)s1 * CH + l * 2);
            vc = *(const unsigned*)(V + (size_t)s1 * CH + l * 2);
        }
        float part = q.x * kx + q.y * ky;
        part += __shfl_xor(part, 1);
        part += __shfl_xor(part, 2);
        part += __shfl_xor(part, 4);
        part += __shfl_xor(part, 8);      // 16 lanes of the head hold the dot
        const float s = part + sbv + bia;
        const float mn = fmaxf(m, s);
        const float scale = __expf(m - mn);
        const float ex = __expf(s - mn);
        den = den * scale + ex;
        a0 = a0 * scale + ex * vx;
        a1 = a1 * scale + ex * vy;
        m = mn;
    }

    const float inv = (den > 0.f) ? 1.f / den : 0.f;   // empty segment -> message 0
    const float2 xv = *(const float2*)(x + (size_t)node * CH + l * 2);
    float v0 = a0 * inv + xv.x;
    float v1 = a1 * inv + xv.y;

    float sum = v0 + v1;
    #pragma unroll
    for (int off = 32; off; off >>= 1) sum += __shfl_xor(sum, off);
    const float mean = sum * (1.f / 128.f);
    const float c0 = v0 - mean, c1 = v1 - mean;
    float vs = c0 * c0 + c1 * c1;
    #pragma unroll
    for (int off = 32; off; off >>= 1) vs += __shfl_xor(vs, off);
    const float rstd = rsqrtf(vs * (1.f / 128.f) + 1e-5f);

    const float2 g = *(const float2*)(gamma + l * 2);
    const float2 bt = *(const float2*)(beta + l * 2);
    float2 o;
    o.x = c0 * rstd * g.x + bt.x;
    o.y = c1 * rstd * g.y + bt.y;
    *(float2*)(out + (size_t)node * CH + l * 2) = o;
}

extern "C" void kernel_launch(void* const* d_in, const int* in_sizes, int n_in,
                              void* d_out, int out_size, void* d_ws, size_t ws_size,
                              hipStream_t stream)
{
    const float* xA     = (const float*)d_in[0];
    const float* xB     = (const float*)d_in[1];
    const float* Wq     = (const float*)d_in[2];
    const float* bq     = (const float*)d_in[3];
    const float* Wk     = (const float*)d_in[4];
    const float* bk     = (const float*)d_in[5];
    const float* Wv     = (const float*)d_in[6];
    const float* bv     = (const float*)d_in[7];
    const float* gamma  = (const float*)d_in[8];
    const float* beta   = (const float*)d_in[9];
    const float* biasAB = (const float*)d_in[10];
    const float* biasBA = (const float*)d_in[11];
    const float* sbAB   = (const float*)d_in[12];
    const float* sbBA   = (const float*)d_in[13];
    const int*   eiAB   = (const int*)d_in[14];
    const int*   eiBA   = (const int*)d_in[15];

    const int n  = in_sizes[0] / CH;     // 100000
    const int nE = in_sizes[12];         // 1000000
    const size_t NC = (size_t)n * CH;

    // ---- workspace carve-up (16B-aligned chunks) ----
    char* p = (char*)d_ws;
    float* Qf = (float*)p;                 p += 2 * NC * sizeof(float);
    unsigned short* Kb = (unsigned short*)p; p += 2 * NC * sizeof(unsigned short);
    unsigned short* Vb = (unsigned short*)p; p += 2 * NC * sizeof(unsigned short);
    unsigned short* Wb = (unsigned short*)p; p += 3 * CH * CH * sizeof(unsigned short);
    int*   srcsAB = (int*)p;               p += (size_t)nE * 4;
    float* sbsAB  = (float*)p;             p += (size_t)nE * 4;
    int*   srcsBA = (int*)p;               p += (size_t)nE * 4;
    float* sbsBA  = (float*)p;             p += (size_t)nE * 4;
    int*   offsAB = (int*)p;               p += (size_t)n * 4;
    int*   offsBA = (int*)p;               p += (size_t)n * 4;
    int*   degAB  = (int*)p;               p += (size_t)n * 4;
    int*   degBA  = (int*)p;               p += (size_t)n * 4;
    int*   curAB  = (int*)p;               p += (size_t)n * 4;
    int*   curBA  = (int*)p;               p += (size_t)n * 4;
    int*   bsumsAB = (int*)p;              p += 256 * 4;
    int*   bsumsBA = (int*)p;              p += 256 * 4;

    float* out = (float*)d_out;

    hipMemsetAsync(degAB, 0, (size_t)4 * n * sizeof(int), stream);  // degAB,degBA,curAB,curBA

    wcvt<<<(3 * CH * CH + 255) / 256, 256, 0, stream>>>(Wq, Wk, Wv, Wb);

    dim3 qkv_grid((n + 63) / 64, 2);
    qkv_mfma<<<qkv_grid, 256, 0, stream>>>(xA, xB, Wb, bq, bk, bv, Qf, Kb, Vb, n);

    const int ebl = (nE + 255) / 256;
    deg_hist<<<ebl, 256, 0, stream>>>(eiAB, degAB, nE);
    deg_hist<<<ebl, 256, 0, stream>>>(eiBA, degBA, nE);

    const int nb = (n + SCAN_BLK - 1) / SCAN_BLK;   // 98 <= 256
    scan_local<<<nb, 256, 0, stream>>>(degAB, offsAB, bsumsAB, n);
    scan_local<<<nb, 256, 0, stream>>>(degBA, offsBA, bsumsBA, n);
    scan_bsums<<<1, 256, 0, stream>>>(bsumsAB, nb);
    scan_bsums<<<1, 256, 0, stream>>>(bsumsBA, nb);
    add_bsums<<<(n + 255) / 256, 256, 0, stream>>>(offsAB, bsumsAB, n);
    add_bsums<<<(n + 255) / 256, 256, 0, stream>>>(offsBA, bsumsBA, n);

    csr_fill<<<ebl, 256, 0, stream>>>(eiAB, sbAB, offsAB, curAB, srcsAB, sbsAB, nE);
    csr_fill<<<ebl, 256, 0, stream>>>(eiBA, sbBA, offsBA, curBA, srcsBA, sbsBA, nE);

    // out_A <- direction BA (dst A, src B); out_B <- direction AB (dst B, src A)
    const int abl = (n + 3) / 4;
    attn_node<<<abl, 256, 0, stream>>>(Qf, Kb + NC, Vb + NC, xA, offsBA, degBA, srcsBA, sbsBA,
                                       biasBA, gamma, beta, out, n);
    attn_node<<<abl, 256, 0, stream>>>(Qf + NC, Kb, Vb, xB, offsAB, degAB, srcsAB, sbsAB,
                                       biasAB, gamma, beta, out + NC, n);
}

// Round 4
// 622.245 us; speedup vs baseline: 7.5433x; 1.2530x over previous
//
#include <hip/hip_runtime.h>

#define CH 128
// head dim = 32, 1/sqrt(32)
#define INV_SQRT_D 0.17677669529663687f
#define SCAN_BLK 1024

typedef __attribute__((ext_vector_type(8))) short bf16x8;
typedef __attribute__((ext_vector_type(4))) float f32x4;

__device__ __forceinline__ unsigned short f2bf(float f) {
    unsigned u = __float_as_uint(f);
    return (unsigned short)((u + 0x7FFFu + ((u >> 16) & 1u)) >> 16);  // RNE
}
__device__ __forceinline__ float bf2f(unsigned short s) {
    return __uint_as_float(((unsigned)s) << 16);
}

// ======================= weight fp32 -> bf16 (tiny one-time pass) =======================
__global__ __launch_bounds__(256) void wcvt(const float* __restrict__ Wq, const float* __restrict__ Wk,
                                            const float* __restrict__ Wv, unsigned short* __restrict__ out)
{
    const int i = blockIdx.x * 256 + threadIdx.x;      // 0 .. 3*16384-1
    if (i >= 3 * CH * CH) return;
    const float* W = (i < CH * CH) ? Wq : (i < 2 * CH * CH) ? Wk : Wv;
    out[i] = f2bf(W[i & (CH * CH - 1)]);
}

// ======================= Fused QKV projection via bf16 MFMA (swapped operands) =======================
// A = W (row=outcol), B = x^T (col=node) => D[outcol][node]; each lane holds 4 consecutive
// outcols of one node -> packed ushort4 stores. Wave w owns outcols [w*32,w*32+32) for all
// 64 block rows and all 3 projections: W loads 24/thread, x via swizzled bf16 LDS.
__global__ __launch_bounds__(256) void qkv_mfma(
    const float* __restrict__ xA, const float* __restrict__ xB,
    const unsigned short* __restrict__ Wb,   // [3][128][128] bf16 (q,k,v), row-major [outcol][k]
    const float* __restrict__ bq, const float* __restrict__ bk, const float* __restrict__ bv,
    unsigned short* __restrict__ Qb,         // [2][n][128] bf16
    unsigned short* __restrict__ KVb,        // [2][n][256] bf16 (K | V interleaved per node)
    int n)
{
    __shared__ __align__(16) char xs[64 * 256];   // 64 rows x 128 bf16, XOR-swizzled
    const int type = blockIdx.y;
    const float* x = type ? xB : xA;
    const int bRow = blockIdx.x * 64;
    const int tid = threadIdx.x;

    // stage x -> bf16 LDS; global reads are 16B/lane fully coalesced (4KB per instr)
    #pragma unroll
    for (int j = 0; j < 8; ++j) {
        const int flat16 = j * 256 + tid;   // 16B chunk index in the 64x128 fp32 tile
        const int row = flat16 >> 5;        // 32 chunks per 512B row
        const int c16 = flat16 & 31;
        float4 v = make_float4(0.f, 0.f, 0.f, 0.f);
        if (bRow + row < n) v = *(const float4*)(x + (size_t)(bRow + row) * CH + c16 * 4);
        unsigned lo = ((unsigned)f2bf(v.y) << 16) | f2bf(v.x);
        unsigned hi = ((unsigned)f2bf(v.w) << 16) | f2bf(v.z);
        const int off = (row * 256 + c16 * 8) ^ ((row & 7) << 4);
        *(uint2*)(xs + off) = make_uint2(lo, hi);
    }
    __syncthreads();

    const int w = tid >> 6, l = tid & 63, lr = l & 15, lg = l >> 4;
    const int colbase = w * 32;

    f32x4 acc[3][2][4];
    #pragma unroll
    for (int p = 0; p < 3; ++p)
        #pragma unroll
        for (int ct = 0; ct < 2; ++ct)
            #pragma unroll
            for (int rt = 0; rt < 4; ++rt)
                acc[p][ct][rt] = (f32x4){0.f, 0.f, 0.f, 0.f};

    #pragma unroll
    for (int kt = 0; kt < 4; ++kt) {
        bf16x8 bx[4];
        #pragma unroll
        for (int rt = 0; rt < 4; ++rt) {
            const int row = rt * 16 + lr;
            const int off = (row * 256 + kt * 64 + lg * 16) ^ ((row & 7) << 4);
            bx[rt] = *(const bf16x8*)(xs + off);
        }
        #pragma unroll
        for (int p = 0; p < 3; ++p) {
            #pragma unroll
            for (int ct = 0; ct < 2; ++ct) {
                const int ocol = colbase + ct * 16 + lr;
                const bf16x8 a = *(const bf16x8*)(Wb + ((size_t)p << 14) + (size_t)ocol * CH + kt * 32 + lg * 8);
                #pragma unroll
                for (int rt = 0; rt < 4; ++rt)
                    acc[p][ct][rt] = __builtin_amdgcn_mfma_f32_16x16x32_bf16(a, bx[rt], acc[p][ct][rt], 0, 0, 0);
            }
        }
    }

    unsigned short* Qo  = Qb  + (size_t)type * n * CH;
    unsigned short* KVo = KVb + (size_t)type * n * 256;
    #pragma unroll
    for (int ct = 0; ct < 2; ++ct) {
        const int c0 = colbase + ct * 16 + lg * 4;   // 4 consecutive outcols
        const float4 bbq = *(const float4*)(bq + c0);
        const float4 bbk = *(const float4*)(bk + c0);
        const float4 bbv = *(const float4*)(bv + c0);
        #pragma unroll
        for (int rt = 0; rt < 4; ++rt) {
            const int node = bRow + rt * 16 + lr;
            if (node >= n) continue;
            const f32x4 aq = acc[0][ct][rt], ak = acc[1][ct][rt], av = acc[2][ct][rt];
            ushort4 q4, k4, v4;
            q4.x = f2bf(aq[0] + bbq.x); q4.y = f2bf(aq[1] + bbq.y);
            q4.z = f2bf(aq[2] + bbq.z); q4.w = f2bf(aq[3] + bbq.w);
            k4.x = f2bf(ak[0] + bbk.x); k4.y = f2bf(ak[1] + bbk.y);
            k4.z = f2bf(ak[2] + bbk.z); k4.w = f2bf(ak[3] + bbk.w);
            v4.x = f2bf(av[0] + bbv.x); v4.y = f2bf(av[1] + bbv.y);
            v4.z = f2bf(av[2] + bbv.z); v4.w = f2bf(av[3] + bbv.w);
            *(ushort4*)(Qo  + (size_t)node * CH  + c0)        = q4;
            *(ushort4*)(KVo + (size_t)node * 256 + c0)        = k4;
            *(ushort4*)(KVo + (size_t)node * 256 + 128 + c0)  = v4;
        }
    }
}

// ======================= CSR build (both directions in one dispatch each) =======================
__global__ __launch_bounds__(256) void deg_hist(const int* __restrict__ eiAB, const int* __restrict__ eiBA,
                                                int* __restrict__ degAB, int* __restrict__ degBA,
                                                int nE, int ebl)
{
    const int dir = blockIdx.x >= ebl;
    const int e = (blockIdx.x - dir * ebl) * 256 + threadIdx.x;
    if (e >= nE) return;
    const int* ei = dir ? eiBA : eiAB;
    int* deg = dir ? degBA : degAB;
    atomicAdd(&deg[ei[nE + e]], 1);
}

__global__ __launch_bounds__(256) void scan_local(const int* __restrict__ degAB, const int* __restrict__ degBA,
                                                  int* __restrict__ offsAB, int* __restrict__ offsBA,
                                                  int* __restrict__ bsums, int n, int nb)
{
    __shared__ int s[256];
    const int dir = blockIdx.x >= nb;
    const int blk = blockIdx.x - dir * nb;
    const int* deg = dir ? degBA : degAB;
    int* offs = dir ? offsBA : offsAB;
    int* bs = bsums + dir * 256;

    const int t = threadIdx.x;
    const int base = blk * SCAN_BLK + t * 4;
    int v0 = 0, v1 = 0, v2 = 0, v3 = 0;
    if (base + 3 < n) {
        int4 q = *(const int4*)(deg + base);
        v0 = q.x; v1 = q.y; v2 = q.z; v3 = q.w;
    } else {
        if (base + 0 < n) v0 = deg[base + 0];
        if (base + 1 < n) v1 = deg[base + 1];
        if (base + 2 < n) v2 = deg[base + 2];
    }
    const int tsum = v0 + v1 + v2 + v3;
    s[t] = tsum;
    __syncthreads();
    for (int off = 1; off < 256; off <<= 1) {
        int add = (t >= off) ? s[t - off] : 0;
        __syncthreads();
        s[t] += add;
        __syncthreads();
    }
    const int excl = s[t] - tsum;
    if (base + 0 < n) offs[base + 0] = excl;
    if (base + 1 < n) offs[base + 1] = excl + v0;
    if (base + 2 < n) offs[base + 2] = excl + v0 + v1;
    if (base + 3 < n) offs[base + 3] = excl + v0 + v1 + v2;
    if (t == 255) bs[blk] = s[255];
}

__global__ __launch_bounds__(256) void scan_bsums(int* __restrict__ bsums, int nb)
{
    __shared__ int s[256];
    int* bs = bsums + blockIdx.x * 256;
    const int t = threadIdx.x;
    int v = (t < nb) ? bs[t] : 0;
    s[t] = v;
    __syncthreads();
    for (int off = 1; off < 256; off <<= 1) {
        int add = (t >= off) ? s[t - off] : 0;
        __syncthreads();
        s[t] += add;
        __syncthreads();
    }
    if (t < nb) bs[t] = s[t] - v;
}

// finalize offs and initialize cursor = offs (cursor then used directly by csr_fill)
__global__ __launch_bounds__(256) void add_bsums(int* __restrict__ offsAB, int* __restrict__ offsBA,
                                                 int* __restrict__ curAB, int* __restrict__ curBA,
                                                 const int* __restrict__ bsums, int n, int nbl)
{
    const int dir = blockIdx.x >= nbl;
    const int i = (blockIdx.x - dir * nbl) * 256 + threadIdx.x;
    if (i >= n) return;
    int* offs = dir ? offsBA : offsAB;
    int* cur  = dir ? curBA  : curAB;
    const int v = offs[i] + bsums[dir * 256 + (i >> 10)];
    offs[i] = v;
    cur[i] = v;
}

// scatter (src, sb) pairs into dst-sorted order
__global__ __launch_bounds__(256) void csr_fill(const int* __restrict__ eiAB, const int* __restrict__ eiBA,
                                                const float* __restrict__ sbAB, const float* __restrict__ sbBA,
                                                int* __restrict__ curAB, int* __restrict__ curBA,
                                                int2* __restrict__ edAB, int2* __restrict__ edBA,
                                                int nE, int ebl)
{
    const int dir = blockIdx.x >= ebl;
    const int e = (blockIdx.x - dir * ebl) * 256 + threadIdx.x;
    if (e >= nE) return;
    const int* ei = dir ? eiBA : eiAB;
    const float* sb = dir ? sbBA : sbAB;
    int* cur = dir ? curBA : curAB;
    int2* ed = dir ? edBA : edAB;
    const int dst = ei[nE + e];
    const int pos = atomicAdd(&cur[dst], 1);
    ed[pos] = make_int2(ei[e], __float_as_int(sb[e]));
}

// ======================= Fused per-node attention + residual + LayerNorm =======================
// One wave per dst node, both directions in one grid; online softmax, 2-deep K/V prefetch.
// Degree term is a per-row constant before LN -> cancels in mean subtraction.
__global__ __launch_bounds__(256) void attn_node(
    const unsigned short* __restrict__ Qb,   // [2][n][128]
    const unsigned short* __restrict__ KVb,  // [2][n][256]
    const float* __restrict__ xA, const float* __restrict__ xB,
    const int* __restrict__ offsAB, const int* __restrict__ offsBA,
    const int* __restrict__ degAB, const int* __restrict__ degBA,
    const int2* __restrict__ edAB, const int2* __restrict__ edBA,
    const float* __restrict__ biasAB, const float* __restrict__ biasBA,
    const float* __restrict__ gamma, const float* __restrict__ beta,
    float* __restrict__ out, int n, int abl)
{
    const int dir = blockIdx.x >= abl;       // 0: dst type A (edges BA), 1: dst type B (edges AB)
    const int node = (blockIdx.x - dir * abl) * 4 + (threadIdx.x >> 6);
    if (node >= n) return;
    const int l = threadIdx.x & 63;
    const int l2 = l * 2;

    const unsigned short* Q  = Qb  + (size_t)dir * n * CH;         // Q of dst type
    const unsigned short* KV = KVb + (size_t)(1 - dir) * n * 256;  // K/V of src type
    const float* x = dir ? xB : xA;
    const int* offs = dir ? offsAB : offsBA;
    const int* deg  = dir ? degAB  : degBA;
    const int2* ed  = dir ? edAB   : edBA;
    const float bia = dir ? biasAB[0] : biasBA[0];
    float* o = out + (size_t)dir * n * CH;

    const unsigned qc = *(const unsigned*)(Q + (size_t)node * CH + l2);
    const float qx = bf2f((unsigned short)qc) * INV_SQRT_D;
    const float qy = bf2f((unsigned short)(qc >> 16)) * INV_SQRT_D;

    const int beg = offs[node];
    const int d = deg[node];

    float m = -3.0e38f, den = 0.f, a0 = 0.f, a1 = 0.f;

    auto proc = [&](int2 e, unsigned kc, unsigned vc) {
        float s = qx * bf2f((unsigned short)kc) + qy * bf2f((unsigned short)(kc >> 16));
        s += __shfl_xor(s, 1);
        s += __shfl_xor(s, 2);
        s += __shfl_xor(s, 4);
        s += __shfl_xor(s, 8);           // 16 lanes of the head now hold the dot
        s += __int_as_float(e.y) + bia;
        const float mn = fmaxf(m, s);
        const float sc = __expf(m - mn);
        const float ex = __expf(s - mn);
        den = den * sc + ex;
        a0 = a0 * sc + ex * bf2f((unsigned short)vc);
        a1 = a1 * sc + ex * bf2f((unsigned short)(vc >> 16));
        m = mn;
    };

    int2 e0 = make_int2(0, 0), e1 = make_int2(0, 0);
    unsigned kc0 = 0, vc0 = 0, kc1 = 0, vc1 = 0;
    if (d > 0) {
        e0 = ed[beg];
        const size_t b = (size_t)e0.x * 256 + l2;
        kc0 = *(const unsigned*)(KV + b); vc0 = *(const unsigned*)(KV + b + 128);
    }
    if (d > 1) {
        e1 = ed[beg + 1];
        const size_t b = (size_t)e1.x * 256 + l2;
        kc1 = *(const unsigned*)(KV + b); vc1 = *(const unsigned*)(KV + b + 128);
    }
    for (int i = 0; i < d; i += 2) {
        const int2 ea = e0; const unsigned ka = kc0, va = vc0;
        const int2 eb = e1; const unsigned kb = kc1, vb = vc1;
        if (i + 2 < d) {
            e0 = ed[beg + i + 2];
            const size_t b = (size_t)e0.x * 256 + l2;
            kc0 = *(const unsigned*)(KV + b); vc0 = *(const unsigned*)(KV + b + 128);
        }
        if (i + 3 < d) {
            e1 = ed[beg + i + 3];
            const size_t b = (size_t)e1.x * 256 + l2;
            kc1 = *(const unsigned*)(KV + b); vc1 = *(const unsigned*)(KV + b + 128);
        }
        proc(ea, ka, va);
        if (i + 1 < d) proc(eb, kb, vb);
    }

    const float inv = (den > 0.f) ? 1.f / den : 0.f;   // empty segment -> message 0
    const float2 xv = *(const float2*)(x + (size_t)node * CH + l2);
    const float v0 = a0 * inv + xv.x;
    const float v1 = a1 * inv + xv.y;

    float sum = v0 + v1;
    #pragma unroll
    for (int off = 32; off; off >>= 1) sum += __shfl_xor(sum, off);
    const float mean = sum * (1.f / 128.f);
    const float c0 = v0 - mean, c1 = v1 - mean;
    float vs = c0 * c0 + c1 * c1;
    #pragma unroll
    for (int off = 32; off; off >>= 1) vs += __shfl_xor(vs, off);
    const float rstd = rsqrtf(vs * (1.f / 128.f) + 1e-5f);

    const float2 g = *(const float2*)(gamma + l2);
    const float2 bt = *(const float2*)(beta + l2);
    float2 ov;
    ov.x = c0 * rstd * g.x + bt.x;
    ov.y = c1 * rstd * g.y + bt.y;
    *(float2*)(o + (size_t)node * CH + l2) = ov;
}

extern "C" void kernel_launch(void* const* d_in, const int* in_sizes, int n_in,
                              void* d_out, int out_size, void* d_ws, size_t ws_size,
                              hipStream_t stream)
{
    const float* xA     = (const float*)d_in[0];
    const float* xB     = (const float*)d_in[1];
    const float* Wq     = (const float*)d_in[2];
    const float* bq     = (const float*)d_in[3];
    const float* Wk     = (const float*)d_in[4];
    const float* bk     = (const float*)d_in[5];
    const float* Wv     = (const float*)d_in[6];
    const float* bv     = (const float*)d_in[7];
    const float* gamma  = (const float*)d_in[8];
    const float* beta   = (const float*)d_in[9];
    const float* biasAB = (const float*)d_in[10];
    const float* biasBA = (const float*)d_in[11];
    const float* sbAB   = (const float*)d_in[12];
    const float* sbBA   = (const float*)d_in[13];
    const int*   eiAB   = (const int*)d_in[14];
    const int*   eiBA   = (const int*)d_in[15];

    const int n  = in_sizes[0] / CH;     // 100000
    const int nE = in_sizes[12];         // 1000000
    const size_t NC = (size_t)n * CH;

    // ---- workspace carve-up (16B aligned) ----
    char* p = (char*)d_ws;
    auto carve = [&](size_t bytes) { char* r = p; p += (bytes + 15) & ~(size_t)15; return r; };
    unsigned short* Qb  = (unsigned short*)carve(2 * NC * 2);            // [2][n][128] bf16
    unsigned short* KVb = (unsigned short*)carve((size_t)2 * n * 256 * 2); // [2][n][256] bf16
    unsigned short* Wb  = (unsigned short*)carve(3 * CH * CH * 2);
    int2* edAB  = (int2*)carve((size_t)nE * 8);
    int2* edBA  = (int2*)carve((size_t)nE * 8);
    int* offsAB = (int*)carve((size_t)n * 4);
    int* offsBA = (int*)carve((size_t)n * 4);
    int* degAB  = (int*)carve((size_t)2 * n * 4);   // degAB,degBA contiguous (one memset)
    int* degBA  = degAB + n;
    int* curAB  = (int*)carve((size_t)n * 4);
    int* curBA  = (int*)carve((size_t)n * 4);
    int* bsums  = (int*)carve(2 * 256 * 4);

    float* out = (float*)d_out;

    hipMemsetAsync(degAB, 0, (size_t)2 * n * sizeof(int), stream);

    wcvt<<<(3 * CH * CH + 255) / 256, 256, 0, stream>>>(Wq, Wk, Wv, Wb);

    dim3 qkv_grid((n + 63) / 64, 2);
    qkv_mfma<<<qkv_grid, 256, 0, stream>>>(xA, xB, Wb, bq, bk, bv, Qb, KVb, n);

    const int ebl = (nE + 255) / 256;
    deg_hist<<<2 * ebl, 256, 0, stream>>>(eiAB, eiBA, degAB, degBA, nE, ebl);

    const int nb = (n + SCAN_BLK - 1) / SCAN_BLK;   // 98 <= 256
    scan_local<<<2 * nb, 256, 0, stream>>>(degAB, degBA, offsAB, offsBA, bsums, n, nb);
    scan_bsums<<<2, 256, 0, stream>>>(bsums, nb);
    const int nbl = (n + 255) / 256;
    add_bsums<<<2 * nbl, 256, 0, stream>>>(offsAB, offsBA, curAB, curBA, bsums, n, nbl);

    csr_fill<<<2 * ebl, 256, 0, stream>>>(eiAB, eiBA, sbAB, sbBA, curAB, curBA, edAB, edBA, nE, ebl);

    const int abl = (n + 3) / 4;
    attn_node<<<2 * abl, 256, 0, stream>>>(Qb, KVb, xA, xB, offsAB, offsBA, degAB, degBA,
                                           edAB, edBA, biasAB, biasBA, gamma, beta, out, n, abl);
}

// Round 5
// 540.724 us; speedup vs baseline: 8.6806x; 1.1508x over previous
//
#include <hip/hip_runtime.h>

#define CH 128
// head dim = 32; fold 1/sqrt(32) * log2(e) into Q so scores are in base-2
#define QSCALE (0.17677669529663687f * 1.4426950408889634f)
#define LOG2E 1.4426950408889634f
#define SCAN_BLK 1024

typedef __attribute__((ext_vector_type(8))) short bf16x8;
typedef __attribute__((ext_vector_type(4))) float f32x4;

__device__ __forceinline__ unsigned short f2bf(float f) {
    unsigned u = __float_as_uint(f);
    return (unsigned short)((u + 0x7FFFu + ((u >> 16) & 1u)) >> 16);  // RNE
}
__device__ __forceinline__ float bf2f(unsigned short s) {
    return __uint_as_float(((unsigned)s) << 16);
}
__device__ __forceinline__ float bflo(unsigned u) { return __uint_as_float(u << 16); }
__device__ __forceinline__ float bfhi(unsigned u) { return __uint_as_float(u & 0xFFFF0000u); }

// ======================= weight fp32 -> bf16 (tiny one-time pass) =======================
__global__ __launch_bounds__(256) void wcvt(const float* __restrict__ Wq, const float* __restrict__ Wk,
                                            const float* __restrict__ Wv, unsigned short* __restrict__ out)
{
    const int i = blockIdx.x * 256 + threadIdx.x;      // 0 .. 3*16384-1
    if (i >= 3 * CH * CH) return;
    const float* W = (i < CH * CH) ? Wq : (i < 2 * CH * CH) ? Wk : Wv;
    out[i] = f2bf(W[i & (CH * CH - 1)]);
}

// ======================= Fused QKV projection via bf16 MFMA (swapped operands) =======================
__global__ __launch_bounds__(256) void qkv_mfma(
    const float* __restrict__ xA, const float* __restrict__ xB,
    const unsigned short* __restrict__ Wb,   // [3][128][128] bf16 (q,k,v), row-major [outcol][k]
    const float* __restrict__ bq, const float* __restrict__ bk, const float* __restrict__ bv,
    unsigned short* __restrict__ Qb,         // [2][n][128] bf16
    unsigned short* __restrict__ KVb,        // [2][n][256] bf16 (K | V interleaved per node)
    int n)
{
    __shared__ __align__(16) char xs[64 * 256];   // 64 rows x 128 bf16, XOR-swizzled
    const int type = blockIdx.y;
    const float* x = type ? xB : xA;
    const int bRow = blockIdx.x * 64;
    const int tid = threadIdx.x;

    #pragma unroll
    for (int j = 0; j < 8; ++j) {
        const int flat16 = j * 256 + tid;
        const int row = flat16 >> 5;
        const int c16 = flat16 & 31;
        float4 v = make_float4(0.f, 0.f, 0.f, 0.f);
        if (bRow + row < n) v = *(const float4*)(x + (size_t)(bRow + row) * CH + c16 * 4);
        unsigned lo = ((unsigned)f2bf(v.y) << 16) | f2bf(v.x);
        unsigned hi = ((unsigned)f2bf(v.w) << 16) | f2bf(v.z);
        const int off = (row * 256 + c16 * 8) ^ ((row & 7) << 4);
        *(uint2*)(xs + off) = make_uint2(lo, hi);
    }
    __syncthreads();

    const int w = tid >> 6, l = tid & 63, lr = l & 15, lg = l >> 4;
    const int colbase = w * 32;

    f32x4 acc[3][2][4];
    #pragma unroll
    for (int p = 0; p < 3; ++p)
        #pragma unroll
        for (int ct = 0; ct < 2; ++ct)
            #pragma unroll
            for (int rt = 0; rt < 4; ++rt)
                acc[p][ct][rt] = (f32x4){0.f, 0.f, 0.f, 0.f};

    #pragma unroll
    for (int kt = 0; kt < 4; ++kt) {
        bf16x8 bx[4];
        #pragma unroll
        for (int rt = 0; rt < 4; ++rt) {
            const int row = rt * 16 + lr;
            const int off = (row * 256 + kt * 64 + lg * 16) ^ ((row & 7) << 4);
            bx[rt] = *(const bf16x8*)(xs + off);
        }
        #pragma unroll
        for (int p = 0; p < 3; ++p) {
            #pragma unroll
            for (int ct = 0; ct < 2; ++ct) {
                const int ocol = colbase + ct * 16 + lr;
                const bf16x8 a = *(const bf16x8*)(Wb + ((size_t)p << 14) + (size_t)ocol * CH + kt * 32 + lg * 8);
                #pragma unroll
                for (int rt = 0; rt < 4; ++rt)
                    acc[p][ct][rt] = __builtin_amdgcn_mfma_f32_16x16x32_bf16(a, bx[rt], acc[p][ct][rt], 0, 0, 0);
            }
        }
    }

    unsigned short* Qo  = Qb  + (size_t)type * n * CH;
    unsigned short* KVo = KVb + (size_t)type * n * 256;
    #pragma unroll
    for (int ct = 0; ct < 2; ++ct) {
        const int c0 = colbase + ct * 16 + lg * 4;
        const float4 bbq = *(const float4*)(bq + c0);
        const float4 bbk = *(const float4*)(bk + c0);
        const float4 bbv = *(const float4*)(bv + c0);
        #pragma unroll
        for (int rt = 0; rt < 4; ++rt) {
            const int node = bRow + rt * 16 + lr;
            if (node >= n) continue;
            const f32x4 aq = acc[0][ct][rt], ak = acc[1][ct][rt], av = acc[2][ct][rt];
            ushort4 q4, k4, v4;
            q4.x = f2bf(aq[0] + bbq.x); q4.y = f2bf(aq[1] + bbq.y);
            q4.z = f2bf(aq[2] + bbq.z); q4.w = f2bf(aq[3] + bbq.w);
            k4.x = f2bf(ak[0] + bbk.x); k4.y = f2bf(ak[1] + bbk.y);
            k4.z = f2bf(ak[2] + bbk.z); k4.w = f2bf(ak[3] + bbk.w);
            v4.x = f2bf(av[0] + bbv.x); v4.y = f2bf(av[1] + bbv.y);
            v4.z = f2bf(av[2] + bbv.z); v4.w = f2bf(av[3] + bbv.w);
            *(ushort4*)(Qo  + (size_t)node * CH  + c0)        = q4;
            *(ushort4*)(KVo + (size_t)node * 256 + c0)        = k4;
            *(ushort4*)(KVo + (size_t)node * 256 + 128 + c0)  = v4;
        }
    }
}

// ======================= CSR build (both directions in one dispatch each) =======================
__global__ __launch_bounds__(256) void deg_hist(const int* __restrict__ eiAB, const int* __restrict__ eiBA,
                                                int* __restrict__ degAB, int* __restrict__ degBA,
                                                int nE, int ebl)
{
    const int dir = blockIdx.x >= ebl;
    const int e = (blockIdx.x - dir * ebl) * 256 + threadIdx.x;
    if (e >= nE) return;
    const int* ei = dir ? eiBA : eiAB;
    int* deg = dir ? degBA : degAB;
    atomicAdd(&deg[ei[nE + e]], 1);
}

__global__ __launch_bounds__(256) void scan_local(const int* __restrict__ degAB, const int* __restrict__ degBA,
                                                  int* __restrict__ offsAB, int* __restrict__ offsBA,
                                                  int* __restrict__ bsums, int n, int nb)
{
    __shared__ int s[256];
    const int dir = blockIdx.x >= nb;
    const int blk = blockIdx.x - dir * nb;
    const int* deg = dir ? degBA : degAB;
    int* offs = dir ? offsBA : offsAB;
    int* bs = bsums + dir * 256;

    const int t = threadIdx.x;
    const int base = blk * SCAN_BLK + t * 4;
    int v0 = 0, v1 = 0, v2 = 0, v3 = 0;
    if (base + 3 < n) {
        int4 q = *(const int4*)(deg + base);
        v0 = q.x; v1 = q.y; v2 = q.z; v3 = q.w;
    } else {
        if (base + 0 < n) v0 = deg[base + 0];
        if (base + 1 < n) v1 = deg[base + 1];
        if (base + 2 < n) v2 = deg[base + 2];
    }
    const int tsum = v0 + v1 + v2 + v3;
    s[t] = tsum;
    __syncthreads();
    for (int off = 1; off < 256; off <<= 1) {
        int add = (t >= off) ? s[t - off] : 0;
        __syncthreads();
        s[t] += add;
        __syncthreads();
    }
    const int excl = s[t] - tsum;
    if (base + 0 < n) offs[base + 0] = excl;
    if (base + 1 < n) offs[base + 1] = excl + v0;
    if (base + 2 < n) offs[base + 2] = excl + v0 + v1;
    if (base + 3 < n) offs[base + 3] = excl + v0 + v1 + v2;
    if (t == 255) bs[blk] = s[255];
}

__global__ __launch_bounds__(256) void scan_bsums(int* __restrict__ bsums, int nb)
{
    __shared__ int s[256];
    int* bs = bsums + blockIdx.x * 256;
    const int t = threadIdx.x;
    int v = (t < nb) ? bs[t] : 0;
    s[t] = v;
    __syncthreads();
    for (int off = 1; off < 256; off <<= 1) {
        int add = (t >= off) ? s[t - off] : 0;
        __syncthreads();
        s[t] += add;
        __syncthreads();
    }
    if (t < nb) bs[t] = s[t] - v;
}

__global__ __launch_bounds__(256) void add_bsums(int* __restrict__ offsAB, int* __restrict__ offsBA,
                                                 int* __restrict__ curAB, int* __restrict__ curBA,
                                                 const int* __restrict__ bsums, int n, int nbl)
{
    const int dir = blockIdx.x >= nbl;
    const int i = (blockIdx.x - dir * nbl) * 256 + threadIdx.x;
    if (i >= n) return;
    int* offs = dir ? offsBA : offsAB;
    int* cur  = dir ? curBA  : curAB;
    const int v = offs[i] + bsums[dir * 256 + (i >> 10)];
    offs[i] = v;
    cur[i] = v;
}

// scatter (src, (sb+bias)*log2e) pairs into dst-sorted order
__global__ __launch_bounds__(256) void csr_fill(const int* __restrict__ eiAB, const int* __restrict__ eiBA,
                                                const float* __restrict__ sbAB, const float* __restrict__ sbBA,
                                                const float* __restrict__ biasAB, const float* __restrict__ biasBA,
                                                int* __restrict__ curAB, int* __restrict__ curBA,
                                                int2* __restrict__ edAB, int2* __restrict__ edBA,
                                                int nE, int ebl)
{
    const int dir = blockIdx.x >= ebl;
    const int e = (blockIdx.x - dir * ebl) * 256 + threadIdx.x;
    if (e >= nE) return;
    const int* ei = dir ? eiBA : eiAB;
    const float* sb = dir ? sbBA : sbAB;
    const float bia = dir ? biasBA[0] : biasAB[0];
    int* cur = dir ? curBA : curAB;
    int2* ed = dir ? edBA : edAB;
    const int dst = ei[nE + e];
    const int pos = atomicAdd(&cur[dst], 1);
    ed[pos] = make_int2(ei[e], __float_as_int((sb[e] + bia) * LOG2E));
}

// ======================= Fused per-node attention + residual + LayerNorm =======================
// One wave per dst node, both directions in one grid. Base-2 online softmax with pairwise
// merge + defer-max (rescale only when max grows by >8 -> P bounded by 2^8, fp32-safe).
// Tail edges padded with score=-inf, V=0 (exact zero contribution).
// Degree term is a per-row constant before LN -> cancels in mean subtraction.
__global__ __launch_bounds__(256) void attn_node(
    const unsigned short* __restrict__ Qb,   // [2][n][128]
    const unsigned short* __restrict__ KVb,  // [2][n][256]
    const float* __restrict__ xA, const float* __restrict__ xB,
    const int* __restrict__ offsAB, const int* __restrict__ offsBA,
    const int* __restrict__ degAB, const int* __restrict__ degBA,
    const int2* __restrict__ edAB, const int2* __restrict__ edBA,
    const float* __restrict__ gamma, const float* __restrict__ beta,
    float* __restrict__ out, int n, int abl)
{
    const int dir = blockIdx.x >= abl;       // 0: dst type A (edges BA), 1: dst type B (edges AB)
    const int node = (blockIdx.x - dir * abl) * 4 + (threadIdx.x >> 6);
    if (node >= n) return;
    const int l = threadIdx.x & 63;
    const int l2 = l * 2;

    const unsigned short* Q  = Qb  + (size_t)dir * n * CH;
    const unsigned short* KV = KVb + (size_t)(1 - dir) * n * 256;
    const float* x = dir ? xB : xA;
    const int* offs = dir ? offsAB : offsBA;
    const int* deg  = dir ? degAB  : degBA;
    const int2* ed  = dir ? edAB   : edBA;
    float* o = out + (size_t)dir * n * CH;

    const unsigned qc = *(const unsigned*)(Q + (size_t)node * CH + l2);
    const float qx = bflo(qc) * QSCALE;
    const float qy = bfhi(qc) * QSCALE;

    const int beg = __builtin_amdgcn_readfirstlane(offs[node]);
    const int d   = __builtin_amdgcn_readfirstlane(deg[node]);

    float m = -3.0e38f, den = 0.f, a0 = 0.f, a1 = 0.f;

    auto loadE = [&](int i, int2& e, unsigned& kc, unsigned& vc) {
        if (i < d) {
            e = ed[beg + i];
            const size_t b = (size_t)e.x * 256 + l2;
            kc = *(const unsigned*)(KV + b);
            vc = *(const unsigned*)(KV + b + 128);
        } else {
            e = make_int2(0, (int)0xFF800000u);   // score -inf
            kc = 0; vc = 0;
        }
    };

    int2 eA0, eA1, eB0, eB1;
    unsigned kA0, vA0, kA1, vA1, kB0, vB0, kB1, vB1;
    if (d > 0) {
        loadE(0, eA0, kA0, vA0); loadE(1, eA1, kA1, vA1);
        loadE(2, eB0, kB0, vB0); loadE(3, eB1, kB1, vB1);
    }

    for (int i = 0; i < d; i += 2) {
        const int2 e0 = eA0, e1 = eA1;
        const unsigned k0 = kA0, v0 = vA0, k1 = kA1, v1 = vA1;
        eA0 = eB0; eA1 = eB1; kA0 = kB0; vA0 = vB0; kA1 = kB1; vA1 = vB1;
        if (i + 4 < d) { loadE(i + 4, eB0, kB0, vB0); loadE(i + 5, eB1, kB1, vB1); }

        // two independent score chains (base-2, bias+sb pre-folded)
        float sa = qx * bflo(k0) + qy * bfhi(k0);
        float sb = qx * bflo(k1) + qy * bfhi(k1);
        sa += __shfl_xor(sa, 1);  sb += __shfl_xor(sb, 1);
        sa += __shfl_xor(sa, 2);  sb += __shfl_xor(sb, 2);
        sa += __shfl_xor(sa, 4);  sb += __shfl_xor(sb, 4);
        sa += __shfl_xor(sa, 8);  sb += __shfl_xor(sb, 8);
        sa += __int_as_float(e0.y);
        sb += __int_as_float(e1.y);

        const float pm = fmaxf(sa, sb);
        if (!__all(pm <= m + 8.f)) {           // defer-max: rescale only on real max growth
            const float mn = fmaxf(m, pm);
            const float sc = exp2f(m - mn);
            den *= sc; a0 *= sc; a1 *= sc; m = mn;
        }
        const float ea = exp2f(sa - m);
        const float eb = exp2f(sb - m);
        den += ea + eb;
        a0 += ea * bflo(v0) + eb * bflo(v1);
        a1 += ea * bfhi(v0) + eb * bfhi(v1);
    }

    const float inv = (den > 0.f) ? 1.f / den : 0.f;   // empty segment -> message 0
    const float2 xv = *(const float2*)(x + (size_t)node * CH + l2);
    const float w0 = a0 * inv + xv.x;
    const float w1 = a1 * inv + xv.y;

    float sum = w0 + w1;
    #pragma unroll
    for (int off = 32; off; off >>= 1) sum += __shfl_xor(sum, off);
    const float mean = sum * (1.f / 128.f);
    const float c0 = w0 - mean, c1 = w1 - mean;
    float vs = c0 * c0 + c1 * c1;
    #pragma unroll
    for (int off = 32; off; off >>= 1) vs += __shfl_xor(vs, off);
    const float rstd = rsqrtf(vs * (1.f / 128.f) + 1e-5f);

    const float2 g = *(const float2*)(gamma + l2);
    const float2 bt = *(const float2*)(beta + l2);
    float2 ov;
    ov.x = c0 * rstd * g.x + bt.x;
    ov.y = c1 * rstd * g.y + bt.y;
    *(float2*)(o + (size_t)node * CH + l2) = ov;
}

extern "C" void kernel_launch(void* const* d_in, const int* in_sizes, int n_in,
                              void* d_out, int out_size, void* d_ws, size_t ws_size,
                              hipStream_t stream)
{
    const float* xA     = (const float*)d_in[0];
    const float* xB     = (const float*)d_in[1];
    const float* Wq     = (const float*)d_in[2];
    const float* bq     = (const float*)d_in[3];
    const float* Wk     = (const float*)d_in[4];
    const float* bk     = (const float*)d_in[5];
    const float* Wv     = (const float*)d_in[6];
    const float* bv     = (const float*)d_in[7];
    const float* gamma  = (const float*)d_in[8];
    const float* beta   = (const float*)d_in[9];
    const float* biasAB = (const float*)d_in[10];
    const float* biasBA = (const float*)d_in[11];
    const float* sbAB   = (const float*)d_in[12];
    const float* sbBA   = (const float*)d_in[13];
    const int*   eiAB   = (const int*)d_in[14];
    const int*   eiBA   = (const int*)d_in[15];

    const int n  = in_sizes[0] / CH;     // 100000
    const int nE = in_sizes[12];         // 1000000
    const size_t NC = (size_t)n * CH;

    // ---- workspace carve-up (16B aligned) ----
    char* p = (char*)d_ws;
    auto carve = [&](size_t bytes) { char* r = p; p += (bytes + 15) & ~(size_t)15; return r; };
    unsigned short* Qb  = (unsigned short*)carve(2 * NC * 2);              // [2][n][128] bf16
    unsigned short* KVb = (unsigned short*)carve((size_t)2 * n * 256 * 2); // [2][n][256] bf16
    unsigned short* Wb  = (unsigned short*)carve(3 * CH * CH * 2);
    int2* edAB  = (int2*)carve((size_t)nE * 8);
    int2* edBA  = (int2*)carve((size_t)nE * 8);
    int* offsAB = (int*)carve((size_t)n * 4);
    int* offsBA = (int*)carve((size_t)n * 4);
    int* degAB  = (int*)carve((size_t)2 * n * 4);   // degAB,degBA contiguous (one memset)
    int* degBA  = degAB + n;
    int* curAB  = (int*)carve((size_t)n * 4);
    int* curBA  = (int*)carve((size_t)n * 4);
    int* bsums  = (int*)carve(2 * 256 * 4);

    float* out = (float*)d_out;

    hipMemsetAsync(degAB, 0, (size_t)2 * n * sizeof(int), stream);

    wcvt<<<(3 * CH * CH + 255) / 256, 256, 0, stream>>>(Wq, Wk, Wv, Wb);

    dim3 qkv_grid((n + 63) / 64, 2);
    qkv_mfma<<<qkv_grid, 256, 0, stream>>>(xA, xB, Wb, bq, bk, bv, Qb, KVb, n);

    const int ebl = (nE + 255) / 256;
    deg_hist<<<2 * ebl, 256, 0, stream>>>(eiAB, eiBA, degAB, degBA, nE, ebl);

    const int nb = (n + SCAN_BLK - 1) / SCAN_BLK;   // 98 <= 256
    scan_local<<<2 * nb, 256, 0, stream>>>(degAB, degBA, offsAB, offsBA, bsums, n, nb);
    scan_bsums<<<2, 256, 0, stream>>>(bsums, nb);
    const int nbl = (n + 255) / 256;
    add_bsums<<<2 * nbl, 256, 0, stream>>>(offsAB, offsBA, curAB, curBA, bsums, n, nbl);

    csr_fill<<<2 * ebl, 256, 0, stream>>>(eiAB, eiBA, sbAB, sbBA, biasAB, biasBA,
                                          curAB, curBA, edAB, edBA, nE, ebl);

    const int abl = (n + 3) / 4;
    attn_node<<<2 * abl, 256, 0, stream>>>(Qb, KVb, xA, xB, offsAB, offsBA, degAB, degBA,
                                           edAB, edBA, gamma, beta, out, n, abl);
}

// Round 7
// 538.509 us; speedup vs baseline: 8.7163x; 1.0041x over previous
//
#include <hip/hip_runtime.h>

#define CH 128
// fold 1/sqrt(32) * log2(e) into Wq/bq so Q·K dots come out in base-2 directly
#define QSCALE (0.17677669529663687f * 1.4426950408889634f)
#define LOG2E 1.4426950408889634f
#define SCAN_BLK 1024

typedef _Float16 f16;
typedef _Float16 f16x2 __attribute__((ext_vector_type(2)));
typedef _Float16 f16x8 __attribute__((ext_vector_type(8)));
typedef __attribute__((ext_vector_type(4))) float f32x4;

__device__ __forceinline__ unsigned pk2(float a, float b) {
    auto h = __builtin_amdgcn_cvt_pkrtz(a, b);     // __fp16 ext_vector(2)
    return __builtin_bit_cast(unsigned, h);
}
__device__ __forceinline__ f16x2 u2h(unsigned u) { return __builtin_bit_cast(f16x2, u); }

// fused cross-lane add via DPP (within 16-lane rows; heads are exactly DPP rows)
__device__ __forceinline__ float dpp_add(float x, const int ctrl) {
    int t;
    switch (ctrl) {   // ctrl must be a literal per builtin; dispatch at compile time
    case 0xB1:  t = __builtin_amdgcn_update_dpp(0, __builtin_bit_cast(int, x), 0xB1, 0xF, 0xF, false); break;
    case 0x4E:  t = __builtin_amdgcn_update_dpp(0, __builtin_bit_cast(int, x), 0x4E, 0xF, 0xF, false); break;
    case 0x124: t = __builtin_amdgcn_update_dpp(0, __builtin_bit_cast(int, x), 0x124, 0xF, 0xF, false); break;
    default:    t = __builtin_amdgcn_update_dpp(0, __builtin_bit_cast(int, x), 0x128, 0xF, 0xF, false); break;
    }
    return x + __builtin_bit_cast(float, t);
}
// sum over the 16 lanes of a head group (quad swaps + row rotations)
__device__ __forceinline__ float head_sum(float x) {
    x = dpp_add(x, 0xB1);    // quad_perm(1,0,3,2)
    x = dpp_add(x, 0x4E);    // quad_perm(2,3,0,1)
    x = dpp_add(x, 0x124);   // row_ror:4
    x = dpp_add(x, 0x128);   // row_ror:8
    return x;
}

__device__ __forceinline__ float hdot(f16x2 a, f16x2 b) {
#if defined(__has_builtin) && __has_builtin(__builtin_amdgcn_fdot2)
    return __builtin_amdgcn_fdot2(__builtin_bit_cast(__fp16 __attribute__((ext_vector_type(2))), a),
                                  __builtin_bit_cast(__fp16 __attribute__((ext_vector_type(2))), b),
                                  0.f, false);
#else
    return (float)a[0] * (float)b[0] + (float)a[1] * (float)b[1];
#endif
}

// ======================= weight fp32 -> f16 (tiny one-time pass; Wq pre-scaled) =======================
__global__ __launch_bounds__(256) void wcvt(const float* __restrict__ Wq, const float* __restrict__ Wk,
                                            const float* __restrict__ Wv, unsigned short* __restrict__ out)
{
    const int i = blockIdx.x * 256 + threadIdx.x;      // 0 .. 3*16384-1
    if (i >= 3 * CH * CH) return;
    const float* W = (i < CH * CH) ? Wq : (i < 2 * CH * CH) ? Wk : Wv;
    const float s = (i < CH * CH) ? QSCALE : 1.f;
    f16 h = (f16)(W[i & (CH * CH - 1)] * s);
    out[i] = __builtin_bit_cast(unsigned short, h);
}

// ======================= Fused QKV projection via f16 MFMA (swapped operands) =======================
// A = W (row=outcol), B = x^T (col=node) => D[outcol][node]; lane holds 4 consecutive outcols
// of one node -> packed stores. Wave w owns outcols [w*32,w*32+32) for all 3 projections.
__global__ __launch_bounds__(256) void qkv_mfma(
    const float* __restrict__ xA, const float* __restrict__ xB,
    const unsigned short* __restrict__ Wb,   // [3][128][128] f16 (q*QSCALE,k,v), [outcol][k]
    const float* __restrict__ bq, const float* __restrict__ bk, const float* __restrict__ bv,
    unsigned short* __restrict__ Qb,         // [2][n][128] f16 (pre-scaled)
    unsigned short* __restrict__ KVb,        // [2][n][256] f16 (K | V per node)
    int n)
{
    __shared__ __align__(16) char xs[64 * 256];   // 64 rows x 128 f16, XOR-swizzled
    const int type = blockIdx.y;
    const float* x = type ? xB : xA;
    const int bRow = blockIdx.x * 64;
    const int tid = threadIdx.x;

    #pragma unroll
    for (int j = 0; j < 8; ++j) {
        const int flat16 = j * 256 + tid;
        const int row = flat16 >> 5;
        const int c16 = flat16 & 31;
        float4 v = make_float4(0.f, 0.f, 0.f, 0.f);
        if (bRow + row < n) v = *(const float4*)(x + (size_t)(bRow + row) * CH + c16 * 4);
        const int off = (row * 256 + c16 * 8) ^ ((row & 7) << 4);
        *(uint2*)(xs + off) = make_uint2(pk2(v.x, v.y), pk2(v.z, v.w));
    }
    __syncthreads();

    const int w = tid >> 6, l = tid & 63, lr = l & 15, lg = l >> 4;
    const int colbase = w * 32;

    f32x4 acc[3][2][4];
    #pragma unroll
    for (int p = 0; p < 3; ++p)
        #pragma unroll
        for (int ct = 0; ct < 2; ++ct)
            #pragma unroll
            for (int rt = 0; rt < 4; ++rt)
                acc[p][ct][rt] = (f32x4){0.f, 0.f, 0.f, 0.f};

    #pragma unroll
    for (int kt = 0; kt < 4; ++kt) {
        f16x8 bx[4];
        #pragma unroll
        for (int rt = 0; rt < 4; ++rt) {
            const int row = rt * 16 + lr;
            const int off = (row * 256 + kt * 64 + lg * 16) ^ ((row & 7) << 4);
            bx[rt] = *(const f16x8*)(xs + off);
        }
        #pragma unroll
        for (int p = 0; p < 3; ++p) {
            #pragma unroll
            for (int ct = 0; ct < 2; ++ct) {
                const int ocol = colbase + ct * 16 + lr;
                const f16x8 a = *(const f16x8*)(Wb + ((size_t)p << 14) + (size_t)ocol * CH + kt * 32 + lg * 8);
                #pragma unroll
                for (int rt = 0; rt < 4; ++rt)
                    acc[p][ct][rt] = __builtin_amdgcn_mfma_f32_16x16x32_f16(a, bx[rt], acc[p][ct][rt], 0, 0, 0);
            }
        }
    }

    unsigned short* Qo  = Qb  + (size_t)type * n * CH;
    unsigned short* KVo = KVb + (size_t)type * n * 256;
    #pragma unroll
    for (int ct = 0; ct < 2; ++ct) {
        const int c0 = colbase + ct * 16 + lg * 4;
        float4 bbq = *(const float4*)(bq + c0);
        bbq.x *= QSCALE; bbq.y *= QSCALE; bbq.z *= QSCALE; bbq.w *= QSCALE;
        const float4 bbk = *(const float4*)(bk + c0);
        const float4 bbv = *(const float4*)(bv + c0);
        #pragma unroll
        for (int rt = 0; rt < 4; ++rt) {
            const int node = bRow + rt * 16 + lr;
            if (node >= n) continue;
            const f32x4 aq = acc[0][ct][rt], ak = acc[1][ct][rt], av = acc[2][ct][rt];
            *(uint2*)(Qo + (size_t)node * CH + c0) =
                make_uint2(pk2(aq[0] + bbq.x, aq[1] + bbq.y), pk2(aq[2] + bbq.z, aq[3] + bbq.w));
            *(uint2*)(KVo + (size_t)node * 256 + c0) =
                make_uint2(pk2(ak[0] + bbk.x, ak[1] + bbk.y), pk2(ak[2] + bbk.z, ak[3] + bbk.w));
            *(uint2*)(KVo + (size_t)node * 256 + 128 + c0) =
                make_uint2(pk2(av[0] + bbv.x, av[1] + bbv.y), pk2(av[2] + bbv.z, av[3] + bbv.w));
        }
    }
}

// ======================= CSR build (both directions in one dispatch each) =======================
__global__ __launch_bounds__(256) void deg_hist(const int* __restrict__ eiAB, const int* __restrict__ eiBA,
                                                int* __restrict__ degAB, int* __restrict__ degBA,
                                                int nE, int ebl)
{
    const int dir = blockIdx.x >= ebl;
    const int e = (blockIdx.x - dir * ebl) * 256 + threadIdx.x;
    if (e >= nE) return;
    const int* ei = dir ? eiBA : eiAB;
    int* deg = dir ? degBA : degAB;
    atomicAdd(&deg[ei[nE + e]], 1);
}

__global__ __launch_bounds__(256) void scan_local(const int* __restrict__ degAB, const int* __restrict__ degBA,
                                                  int* __restrict__ offsAB, int* __restrict__ offsBA,
                                                  int* __restrict__ bsums, int n, int nb)
{
    __shared__ int s[256];
    const int dir = blockIdx.x >= nb;
    const int blk = blockIdx.x - dir * nb;
    const int* deg = dir ? degBA : degAB;
    int* offs = dir ? offsBA : offsAB;
    int* bs = bsums + dir * 256;

    const int t = threadIdx.x;
    const int base = blk * SCAN_BLK + t * 4;
    int v0 = 0, v1 = 0, v2 = 0, v3 = 0;
    if (base + 3 < n) {
        int4 q = *(const int4*)(deg + base);
        v0 = q.x; v1 = q.y; v2 = q.z; v3 = q.w;
    } else {
        if (base + 0 < n) v0 = deg[base + 0];
        if (base + 1 < n) v1 = deg[base + 1];
        if (base + 2 < n) v2 = deg[base + 2];
    }
    const int tsum = v0 + v1 + v2 + v3;
    s[t] = tsum;
    __syncthreads();
    for (int off = 1; off < 256; off <<= 1) {
        int add = (t >= off) ? s[t - off] : 0;
        __syncthreads();
        s[t] += add;
        __syncthreads();
    }
    const int excl = s[t] - tsum;
    if (base + 0 < n) offs[base + 0] = excl;
    if (base + 1 < n) offs[base + 1] = excl + v0;
    if (base + 2 < n) offs[base + 2] = excl + v0 + v1;
    if (base + 3 < n) offs[base + 3] = excl + v0 + v1 + v2;
    if (t == 255) bs[blk] = s[255];
}

__global__ __launch_bounds__(256) void scan_bsums(int* __restrict__ bsums, int nb)
{
    __shared__ int s[256];
    int* bs = bsums + blockIdx.x * 256;
    const int t = threadIdx.x;
    int v = (t < nb) ? bs[t] : 0;
    s[t] = v;
    __syncthreads();
    for (int off = 1; off < 256; off <<= 1) {
        int add = (t >= off) ? s[t - off] : 0;
        __syncthreads();
        s[t] += add;
        __syncthreads();
    }
    if (t < nb) bs[t] = s[t] - v;
}

__global__ __launch_bounds__(256) void add_bsums(int* __restrict__ offsAB, int* __restrict__ offsBA,
                                                 int* __restrict__ curAB, int* __restrict__ curBA,
                                                 const int* __restrict__ bsums, int n, int nbl)
{
    const int dir = blockIdx.x >= nbl;
    const int i = (blockIdx.x - dir * nbl) * 256 + threadIdx.x;
    if (i >= n) return;
    int* offs = dir ? offsBA : offsAB;
    int* cur  = dir ? curBA  : curAB;
    const int v = offs[i] + bsums[dir * 256 + (i >> 10)];
    offs[i] = v;
    cur[i] = v;
}

// scatter (src, (sb+bias)*log2e) pairs into dst-sorted order
__global__ __launch_bounds__(256) void csr_fill(const int* __restrict__ eiAB, const int* __restrict__ eiBA,
                                                const float* __restrict__ sbAB, const float* __restrict__ sbBA,
                                                const float* __restrict__ biasAB, const float* __restrict__ biasBA,
                                                int* __restrict__ curAB, int* __restrict__ curBA,
                                                int2* __restrict__ edAB, int2* __restrict__ edBA,
                                                int nE, int ebl)
{
    const int dir = blockIdx.x >= ebl;
    const int e = (blockIdx.x - dir * ebl) * 256 + threadIdx.x;
    if (e >= nE) return;
    const int* ei = dir ? eiBA : eiAB;
    const float* sb = dir ? sbBA : sbAB;
    const float bia = dir ? biasBA[0] : biasAB[0];
    int* cur = dir ? curBA : curAB;
    int2* ed = dir ? edBA : edAB;
    const int dst = ei[nE + e];
    const int pos = atomicAdd(&cur[dst], 1);
    ed[pos] = make_int2(ei[e], __float_as_int((sb[e] + bia) * LOG2E));
}

// ======================= Fused per-node attention + residual + LayerNorm =======================
// One wave per dst node, both directions in one grid. Base-2 online softmax, pairwise +
// defer-max; per-edge dot via v_dot2_f32_f16, head reduction via DPP adds, V accumulated
// in packed f16 (v_pk_fma_f16). Degree term cancels in LN mean subtraction.
__global__ __launch_bounds__(256) void attn_node(
    const unsigned short* __restrict__ Qb,   // [2][n][128] f16 pre-scaled
    const unsigned short* __restrict__ KVb,  // [2][n][256] f16
    const float* __restrict__ xA, const float* __restrict__ xB,
    const int* __restrict__ offsAB, const int* __restrict__ offsBA,
    const int* __restrict__ degAB, const int* __restrict__ degBA,
    const int2* __restrict__ edAB, const int2* __restrict__ edBA,
    const float* __restrict__ gamma, const float* __restrict__ beta,
    float* __restrict__ out, int n, int abl)
{
    const int dir = blockIdx.x >= abl;       // 0: dst type A (edges BA), 1: dst type B (edges AB)
    const int node = (blockIdx.x - dir * abl) * 4 + (threadIdx.x >> 6);
    if (node >= n) return;
    const int l = threadIdx.x & 63;
    const int l2 = l * 2;

    const unsigned short* Q = Qb + (size_t)dir * n * CH;
    const char* KV = (const char*)(KVb + (size_t)(1 - dir) * n * 256);   // byte base of src type
    const float* x = dir ? xB : xA;
    const int* offs = dir ? offsAB : offsBA;
    const int* deg  = dir ? degAB  : degBA;
    const int2* ed  = dir ? edAB   : edBA;
    float* o = out + (size_t)dir * n * CH;

    const f16x2 qp = u2h(*(const unsigned*)(Q + (size_t)node * CH + l2));
    const unsigned lb = (unsigned)l2 * 2u;   // byte offset of this lane's channel pair

    const int beg = __builtin_amdgcn_readfirstlane(offs[node]);
    const int d   = __builtin_amdgcn_readfirstlane(deg[node]);

    float m = -3.0e38f, den = 0.f;
    f16x2 a01 = (f16x2){(f16)0.f, (f16)0.f};

    auto loadE = [&](int i, int2& e, unsigned& kc, unsigned& vc) {
        if (i < d) {
            e = ed[beg + i];
            const unsigned b = (unsigned)e.x * 512u + lb;
            kc = *(const unsigned*)(KV + b);
            vc = *(const unsigned*)(KV + b + 256);
        } else {
            e = make_int2(0, (int)0xFF800000u);   // score -inf
            kc = 0; vc = 0;
        }
    };

    int2 eA0, eA1, eB0, eB1;
    unsigned kA0, vA0, kA1, vA1, kB0, vB0, kB1, vB1;
    if (d > 0) {
        loadE(0, eA0, kA0, vA0); loadE(1, eA1, kA1, vA1);
        loadE(2, eB0, kB0, vB0); loadE(3, eB1, kB1, vB1);
    }

    for (int i = 0; i < d; i += 2) {
        const int2 e0 = eA0, e1 = eA1;
        const unsigned k0 = kA0, v0 = vA0, k1 = kA1, v1 = vA1;
        eA0 = eB0; eA1 = eB1; kA0 = kB0; vA0 = vB0; kA1 = kB1; vA1 = vB1;
        if (i + 4 < d) { loadE(i + 4, eB0, kB0, vB0); loadE(i + 5, eB1, kB1, vB1); }

        // two independent base-2 score chains
        float sa = hdot(qp, u2h(k0));
        float sb = hdot(qp, u2h(k1));
        sa = head_sum(sa);
        sb = head_sum(sb);
        sa += __int_as_float(e0.y);
        sb += __int_as_float(e1.y);

        const float pm = fmaxf(sa, sb);
        if (!__all(pm <= m + 8.f)) {           // defer-max: rescale only on real max growth
            const float mn = fmaxf(m, pm);
            const float sc = exp2f(m - mn);
            den *= sc;
            a01 *= u2h(pk2(sc, sc));
            m = mn;
        }
        const float ea = exp2f(sa - m);
        const float eb = exp2f(sb - m);
        den += ea + eb;
        a01 += u2h(pk2(ea, ea)) * u2h(v0);
        a01 += u2h(pk2(eb, eb)) * u2h(v1);
    }

    const float inv = (den > 0.f) ? 1.f / den : 0.f;   // empty segment -> message 0
    const float2 xv = *(const float2*)(x + (size_t)node * CH + l2);
    const float w0 = (float)a01[0] * inv + xv.x;
    const float w1 = (float)a01[1] * inv + xv.y;

    float sum = w0 + w1;
    #pragma unroll
    for (int off = 32; off; off >>= 1) sum += __shfl_xor(sum, off);
    const float mean = sum * (1.f / 128.f);
    const float c0 = w0 - mean, c1 = w1 - mean;
    float vs = c0 * c0 + c1 * c1;
    #pragma unroll
    for (int off = 32; off; off >>= 1) vs += __shfl_xor(vs, off);
    const float rstd = rsqrtf(vs * (1.f / 128.f) + 1e-5f);

    const float2 g = *(const float2*)(gamma + l2);
    const float2 bt = *(const float2*)(beta + l2);
    float2 ov;
    ov.x = c0 * rstd * g.x + bt.x;
    ov.y = c1 * rstd * g.y + bt.y;
    *(float2*)(o + (size_t)node * CH + l2) = ov;
}

extern "C" void kernel_launch(void* const* d_in, const int* in_sizes, int n_in,
                              void* d_out, int out_size, void* d_ws, size_t ws_size,
                              hipStream_t stream)
{
    const float* xA     = (const float*)d_in[0];
    const float* xB     = (const float*)d_in[1];
    const float* Wq     = (const float*)d_in[2];
    const float* bq     = (const float*)d_in[3];
    const float* Wk     = (const float*)d_in[4];
    const float* bk     = (const float*)d_in[5];
    const float* Wv     = (const float*)d_in[6];
    const float* bv     = (const float*)d_in[7];
    const float* gamma  = (const float*)d_in[8];
    const float* beta   = (const float*)d_in[9];
    const float* biasAB = (const float*)d_in[10];
    const float* biasBA = (const float*)d_in[11];
    const float* sbAB   = (const float*)d_in[12];
    const float* sbBA   = (const float*)d_in[13];
    const int*   eiAB   = (const int*)d_in[14];
    const int*   eiBA   = (const int*)d_in[15];

    const int n  = in_sizes[0] / CH;     // 100000
    const int nE = in_sizes[12];         // 1000000
    const size_t NC = (size_t)n * CH;

    // ---- workspace carve-up (16B aligned) ----
    char* p = (char*)d_ws;
    auto carve = [&](size_t bytes) { char* r = p; p += (bytes + 15) & ~(size_t)15; return r; };
    unsigned short* Qb  = (unsigned short*)carve(2 * NC * 2);              // [2][n][128] f16
    unsigned short* KVb = (unsigned short*)carve((size_t)2 * n * 256 * 2); // [2][n][256] f16
    unsigned short* Wb  = (unsigned short*)carve(3 * CH * CH * 2);
    int2* edAB  = (int2*)carve((size_t)nE * 8);
    int2* edBA  = (int2*)carve((size_t)nE * 8);
    int* offsAB = (int*)carve((size_t)n * 4);
    int* offsBA = (int*)carve((size_t)n * 4);
    int* degAB  = (int*)carve((size_t)2 * n * 4);   // degAB,degBA contiguous (one memset)
    int* degBA  = degAB + n;
    int* curAB  = (int*)carve((size_t)n * 4);
    int* curBA  = (int*)carve((size_t)n * 4);
    int* bsums  = (int*)carve(2 * 256 * 4);

    float* out = (float*)d_out;

    (void)hipMemsetAsync(degAB, 0, (size_t)2 * n * sizeof(int), stream);

    wcvt<<<(3 * CH * CH + 255) / 256, 256, 0, stream>>>(Wq, Wk, Wv, Wb);

    dim3 qkv_grid((n + 63) / 64, 2);
    qkv_mfma<<<qkv_grid, 256, 0, stream>>>(xA, xB, Wb, bq, bk, bv, Qb, KVb, n);

    const int ebl = (nE + 255) / 256;
    deg_hist<<<2 * ebl, 256, 0, stream>>>(eiAB, eiBA, degAB, degBA, nE, ebl);

    const int nb = (n + SCAN_BLK - 1) / SCAN_BLK;   // 98 <= 256
    scan_local<<<2 * nb, 256, 0, stream>>>(degAB, degBA, offsAB, offsBA, bsums, n, nb);
    scan_bsums<<<2, 256, 0, stream>>>(bsums, nb);
    const int nbl = (n + 255) / 256;
    add_bsums<<<2 * nbl, 256, 0, stream>>>(offsAB, offsBA, curAB, curBA, bsums, n, nbl);

    csr_fill<<<2 * ebl, 256, 0, stream>>>(eiAB, eiBA, sbAB, sbBA, biasAB, biasBA,
                                          curAB, curBA, edAB, edBA, nE, ebl);

    const int abl = (n + 3) / 4;
    attn_node<<<2 * abl, 256, 0, stream>>>(Qb, KVb, xA, xB, offsAB, offsBA, degAB, degBA,
                                           edAB, edBA, gamma, beta, out, n, abl);
}

// Round 8
// 536.749 us; speedup vs baseline: 8.7449x; 1.0033x over previous
//
#include <hip/hip_runtime.h>

#define CH 128
// fold 1/sqrt(32) * log2(e) into Wq/bq so Q·K dots come out in base-2 directly
#define QSCALE (0.17677669529663687f * 1.4426950408889634f)
#define LOG2E 1.4426950408889634f
#define SCAN_BLK 1024

typedef _Float16 f16;
typedef _Float16 f16x2 __attribute__((ext_vector_type(2)));
typedef _Float16 f16x8 __attribute__((ext_vector_type(8)));
typedef __attribute__((ext_vector_type(4))) float f32x4;

__device__ __forceinline__ unsigned pk2(float a, float b) {
    auto h = __builtin_amdgcn_cvt_pkrtz(a, b);     // __fp16 ext_vector(2)
    return __builtin_bit_cast(unsigned, h);
}
__device__ __forceinline__ f16x2 u2h(unsigned u) { return __builtin_bit_cast(f16x2, u); }

// fused cross-lane add via DPP (within 16-lane rows; heads are exactly DPP rows)
__device__ __forceinline__ float dpp_add(float x, const int ctrl) {
    int t;
    switch (ctrl) {
    case 0xB1:  t = __builtin_amdgcn_update_dpp(0, __builtin_bit_cast(int, x), 0xB1, 0xF, 0xF, false); break;
    case 0x4E:  t = __builtin_amdgcn_update_dpp(0, __builtin_bit_cast(int, x), 0x4E, 0xF, 0xF, false); break;
    case 0x124: t = __builtin_amdgcn_update_dpp(0, __builtin_bit_cast(int, x), 0x124, 0xF, 0xF, false); break;
    default:    t = __builtin_amdgcn_update_dpp(0, __builtin_bit_cast(int, x), 0x128, 0xF, 0xF, false); break;
    }
    return x + __builtin_bit_cast(float, t);
}
__device__ __forceinline__ float head_sum(float x) {
    x = dpp_add(x, 0xB1);    // quad_perm(1,0,3,2)
    x = dpp_add(x, 0x4E);    // quad_perm(2,3,0,1)
    x = dpp_add(x, 0x124);   // row_ror:4
    x = dpp_add(x, 0x128);   // row_ror:8
    return x;
}

__device__ __forceinline__ float hdot(f16x2 a, f16x2 b) {
#if defined(__has_builtin) && __has_builtin(__builtin_amdgcn_fdot2)
    return __builtin_amdgcn_fdot2(__builtin_bit_cast(__fp16 __attribute__((ext_vector_type(2))), a),
                                  __builtin_bit_cast(__fp16 __attribute__((ext_vector_type(2))), b),
                                  0.f, false);
#else
    return (float)a[0] * (float)b[0] + (float)a[1] * (float)b[1];
#endif
}

// ======================= weight fp32 -> f16 (tiny one-time pass; Wq pre-scaled) =======================
__global__ __launch_bounds__(256) void wcvt(const float* __restrict__ Wq, const float* __restrict__ Wk,
                                            const float* __restrict__ Wv, unsigned short* __restrict__ out)
{
    const int i = blockIdx.x * 256 + threadIdx.x;      // 0 .. 3*16384-1
    if (i >= 3 * CH * CH) return;
    const float* W = (i < CH * CH) ? Wq : (i < 2 * CH * CH) ? Wk : Wv;
    const float s = (i < CH * CH) ? QSCALE : 1.f;
    f16 h = (f16)(W[i & (CH * CH - 1)] * s);
    out[i] = __builtin_bit_cast(unsigned short, h);
}

// ======================= Fused QKV projection via f16 MFMA (swapped operands) =======================
// A = W (row=outcol), B = x^T (col=node) => D[outcol][node]. Epilogue transposes through LDS
// (48 KB: Q|K|V planes of 64x256B, XOR-swizzled) so global stores are contiguous dwordx4
// with consecutive lanes -> fully coalesced.
__global__ __launch_bounds__(256) void qkv_mfma(
    const float* __restrict__ xA, const float* __restrict__ xB,
    const unsigned short* __restrict__ Wb,   // [3][128][128] f16 (q*QSCALE,k,v), [outcol][k]
    const float* __restrict__ bq, const float* __restrict__ bk, const float* __restrict__ bv,
    unsigned short* __restrict__ Qb,         // [2][n][128] f16 (pre-scaled)
    unsigned short* __restrict__ KVb,        // [2][n][256] f16 (K | V per node)
    int n)
{
    __shared__ __align__(16) char lds[49152];   // staging (16K) then Q/K/V epilogue planes
    const int type = blockIdx.y;
    const float* x = type ? xB : xA;
    const int bRow = blockIdx.x * 64;
    const int tid = threadIdx.x;

    // stage x -> f16 LDS (first 16 KB), XOR-swizzled
    #pragma unroll
    for (int j = 0; j < 8; ++j) {
        const int flat16 = j * 256 + tid;
        const int row = flat16 >> 5;
        const int c16 = flat16 & 31;
        float4 v = make_float4(0.f, 0.f, 0.f, 0.f);
        if (bRow + row < n) v = *(const float4*)(x + (size_t)(bRow + row) * CH + c16 * 4);
        const int off = (row * 256 + c16 * 8) ^ ((row & 7) << 4);
        *(uint2*)(lds + off) = make_uint2(pk2(v.x, v.y), pk2(v.z, v.w));
    }
    __syncthreads();

    const int w = tid >> 6, l = tid & 63, lr = l & 15, lg = l >> 4;
    const int colbase = w * 32;

    f32x4 acc[3][2][4];
    #pragma unroll
    for (int p = 0; p < 3; ++p)
        #pragma unroll
        for (int ct = 0; ct < 2; ++ct)
            #pragma unroll
            for (int rt = 0; rt < 4; ++rt)
                acc[p][ct][rt] = (f32x4){0.f, 0.f, 0.f, 0.f};

    #pragma unroll
    for (int kt = 0; kt < 4; ++kt) {
        f16x8 bx[4];
        #pragma unroll
        for (int rt = 0; rt < 4; ++rt) {
            const int row = rt * 16 + lr;
            const int off = (row * 256 + kt * 64 + lg * 16) ^ ((row & 7) << 4);
            bx[rt] = *(const f16x8*)(lds + off);
        }
        #pragma unroll
        for (int p = 0; p < 3; ++p) {
            #pragma unroll
            for (int ct = 0; ct < 2; ++ct) {
                const int ocol = colbase + ct * 16 + lr;
                const f16x8 a = *(const f16x8*)(Wb + ((size_t)p << 14) + (size_t)ocol * CH + kt * 32 + lg * 8);
                #pragma unroll
                for (int rt = 0; rt < 4; ++rt)
                    acc[p][ct][rt] = __builtin_amdgcn_mfma_f32_16x16x32_f16(a, bx[rt], acc[p][ct][rt], 0, 0, 0);
            }
        }
    }

    __syncthreads();   // staging region about to be overwritten by epilogue planes

    // ---- epilogue pass 1: fragments -> LDS planes (Q:0, K:16K, V:32K), swizzled 8B writes ----
    #pragma unroll
    for (int p = 0; p < 3; ++p) {
        const float* bias = (p == 0) ? bq : (p == 1) ? bk : bv;
        #pragma unroll
        for (int ct = 0; ct < 2; ++ct) {
            const int c0 = colbase + ct * 16 + lg * 4;
            float4 bb = *(const float4*)(bias + c0);
            if (p == 0) { bb.x *= QSCALE; bb.y *= QSCALE; bb.z *= QSCALE; bb.w *= QSCALE; }
            const int cb = w * 64 + ct * 32 + lg * 8;   // byte offset within 256B row
            #pragma unroll
            for (int rt = 0; rt < 4; ++rt) {
                const int nodeloc = rt * 16 + lr;
                const f32x4 a4 = acc[p][ct][rt];
                const uint2 val = make_uint2(pk2(a4[0] + bb.x, a4[1] + bb.y),
                                             pk2(a4[2] + bb.z, a4[3] + bb.w));
                *(uint2*)(lds + p * 16384 + nodeloc * 256 + (cb ^ ((nodeloc & 7) << 4))) = val;
            }
        }
    }
    __syncthreads();

    // ---- epilogue pass 2: LDS -> global, contiguous 16B chunks, consecutive lanes ----
    unsigned short* Qo  = Qb  + (size_t)type * n * CH;
    unsigned short* KVo = KVb + (size_t)type * n * 256;
    #pragma unroll
    for (int j = 0; j < 4; ++j) {                       // Q plane: 16 KB
        const int flat = j * 256 + tid;
        const int row = flat >> 4, c16 = flat & 15;
        const uint4 val = *(const uint4*)(lds + row * 256 + ((c16 ^ (row & 7)) << 4));
        const int node = bRow + row;
        if (node < n) *(uint4*)(Qo + (size_t)node * CH + c16 * 8) = val;
    }
    #pragma unroll
    for (int j = 0; j < 8; ++j) {                       // K|V interleaved: 32 KB
        const int flat = j * 256 + tid;
        const int row = flat >> 5, c16 = flat & 31;
        const int cc = c16 & 15, sel = c16 >> 4;        // 0=K, 1=V
        const uint4 val = *(const uint4*)(lds + 16384 + sel * 16384 + row * 256 + ((cc ^ (row & 7)) << 4));
        const int node = bRow + row;
        if (node < n) *(uint4*)(KVo + (size_t)node * 256 + c16 * 8) = val;
    }
}

// ======================= CSR build (both directions in one dispatch each) =======================
__global__ __launch_bounds__(256) void deg_hist(const int* __restrict__ eiAB, const int* __restrict__ eiBA,
                                                int* __restrict__ degAB, int* __restrict__ degBA,
                                                int nE, int ebl)
{
    const int dir = blockIdx.x >= ebl;
    const int e = ((blockIdx.x - dir * ebl) * 256 + threadIdx.x) * 4;
    if (e >= nE) return;
    const int* ei = dir ? eiBA : eiAB;
    int* deg = dir ? degBA : degAB;
    if (e + 3 < nE) {
        const int4 d4 = *(const int4*)(ei + nE + e);
        atomicAdd(&deg[d4.x], 1); atomicAdd(&deg[d4.y], 1);
        atomicAdd(&deg[d4.z], 1); atomicAdd(&deg[d4.w], 1);
    } else {
        for (int j = e; j < nE; ++j) atomicAdd(&deg[ei[nE + j]], 1);
    }
}

__global__ __launch_bounds__(256) void scan_local(const int* __restrict__ degAB, const int* __restrict__ degBA,
                                                  int* __restrict__ offsAB, int* __restrict__ offsBA,
                                                  int* __restrict__ bsums, int n, int nb)
{
    __shared__ int s[256];
    const int dir = blockIdx.x >= nb;
    const int blk = blockIdx.x - dir * nb;
    const int* deg = dir ? degBA : degAB;
    int* offs = dir ? offsBA : offsAB;
    int* bs = bsums + dir * 256;

    const int t = threadIdx.x;
    const int base = blk * SCAN_BLK + t * 4;
    int v0 = 0, v1 = 0, v2 = 0, v3 = 0;
    if (base + 3 < n) {
        int4 q = *(const int4*)(deg + base);
        v0 = q.x; v1 = q.y; v2 = q.z; v3 = q.w;
    } else {
        if (base + 0 < n) v0 = deg[base + 0];
        if (base + 1 < n) v1 = deg[base + 1];
        if (base + 2 < n) v2 = deg[base + 2];
    }
    const int tsum = v0 + v1 + v2 + v3;
    s[t] = tsum;
    __syncthreads();
    for (int off = 1; off < 256; off <<= 1) {
        int add = (t >= off) ? s[t - off] : 0;
        __syncthreads();
        s[t] += add;
        __syncthreads();
    }
    const int excl = s[t] - tsum;
    if (base + 0 < n) offs[base + 0] = excl;
    if (base + 1 < n) offs[base + 1] = excl + v0;
    if (base + 2 < n) offs[base + 2] = excl + v0 + v1;
    if (base + 3 < n) offs[base + 3] = excl + v0 + v1 + v2;
    if (t == 255) bs[blk] = s[255];
}

__global__ __launch_bounds__(256) void scan_bsums(int* __restrict__ bsums, int nb)
{
    __shared__ int s[256];
    int* bs = bsums + blockIdx.x * 256;
    const int t = threadIdx.x;
    int v = (t < nb) ? bs[t] : 0;
    s[t] = v;
    __syncthreads();
    for (int off = 1; off < 256; off <<= 1) {
        int add = (t >= off) ? s[t - off] : 0;
        __syncthreads();
        s[t] += add;
        __syncthreads();
    }
    if (t < nb) bs[t] = s[t] - v;
}

__global__ __launch_bounds__(256) void add_bsums(int* __restrict__ offsAB, int* __restrict__ offsBA,
                                                 int* __restrict__ curAB, int* __restrict__ curBA,
                                                 const int* __restrict__ bsums, int n, int nbl)
{
    const int dir = blockIdx.x >= nbl;
    const int i = (blockIdx.x - dir * nbl) * 256 + threadIdx.x;
    if (i >= n) return;
    int* offs = dir ? offsBA : offsAB;
    int* cur  = dir ? curBA  : curAB;
    const int v = offs[i] + bsums[dir * 256 + (i >> 10)];
    offs[i] = v;
    cur[i] = v;
}

// scatter (src, (sb+bias)*log2e) pairs into dst-sorted order; 4 edges/thread
__global__ __launch_bounds__(256) void csr_fill(const int* __restrict__ eiAB, const int* __restrict__ eiBA,
                                                const float* __restrict__ sbAB, const float* __restrict__ sbBA,
                                                const float* __restrict__ biasAB, const float* __restrict__ biasBA,
                                                int* __restrict__ curAB, int* __restrict__ curBA,
                                                int2* __restrict__ edAB, int2* __restrict__ edBA,
                                                int nE, int ebl)
{
    const int dir = blockIdx.x >= ebl;
    const int e = ((blockIdx.x - dir * ebl) * 256 + threadIdx.x) * 4;
    if (e >= nE) return;
    const int* ei = dir ? eiBA : eiAB;
    const float* sb = dir ? sbBA : sbAB;
    const float bia = dir ? biasBA[0] : biasAB[0];
    int* cur = dir ? curBA : curAB;
    int2* ed = dir ? edBA : edAB;
    if (e + 3 < nE) {
        const int4 s4 = *(const int4*)(ei + e);
        const int4 d4 = *(const int4*)(ei + nE + e);
        const float4 b4 = *(const float4*)(sb + e);
        int p0 = atomicAdd(&cur[d4.x], 1); ed[p0] = make_int2(s4.x, __float_as_int((b4.x + bia) * LOG2E));
        int p1 = atomicAdd(&cur[d4.y], 1); ed[p1] = make_int2(s4.y, __float_as_int((b4.y + bia) * LOG2E));
        int p2 = atomicAdd(&cur[d4.z], 1); ed[p2] = make_int2(s4.z, __float_as_int((b4.z + bia) * LOG2E));
        int p3 = atomicAdd(&cur[d4.w], 1); ed[p3] = make_int2(s4.w, __float_as_int((b4.w + bia) * LOG2E));
    } else {
        for (int j = e; j < nE; ++j) {
            const int pos = atomicAdd(&cur[ei[nE + j]], 1);
            ed[pos] = make_int2(ei[j], __float_as_int((sb[j] + bia) * LOG2E));
        }
    }
}

// ======================= Fused per-node attention + residual + LayerNorm =======================
// One wave per dst node. Base-2 online softmax, pairwise + defer-max; fdot2 + DPP head sums;
// packed f16 V accumulation. 8-edge ping-pong prefetch (two groups of 4, no register shifts).
__global__ __launch_bounds__(256) void attn_node(
    const unsigned short* __restrict__ Qb,   // [2][n][128] f16 pre-scaled
    const unsigned short* __restrict__ KVb,  // [2][n][256] f16
    const float* __restrict__ xA, const float* __restrict__ xB,
    const int* __restrict__ offsAB, const int* __restrict__ offsBA,
    const int* __restrict__ degAB, const int* __restrict__ degBA,
    const int2* __restrict__ edAB, const int2* __restrict__ edBA,
    const float* __restrict__ gamma, const float* __restrict__ beta,
    float* __restrict__ out, int n, int abl)
{
    const int dir = blockIdx.x >= abl;       // 0: dst type A (edges BA), 1: dst type B (edges AB)
    const int node = (blockIdx.x - dir * abl) * 4 + (threadIdx.x >> 6);
    if (node >= n) return;
    const int l = threadIdx.x & 63;
    const int l2 = l * 2;

    const unsigned short* Q = Qb + (size_t)dir * n * CH;
    const char* KV = (const char*)(KVb + (size_t)(1 - dir) * n * 256);
    const float* x = dir ? xB : xA;
    const int* offs = dir ? offsAB : offsBA;
    const int* deg  = dir ? degAB  : degBA;
    const int2* ed  = dir ? edAB   : edBA;
    float* o = out + (size_t)dir * n * CH;

    const f16x2 qp = u2h(*(const unsigned*)(Q + (size_t)node * CH + l2));
    const unsigned lb = (unsigned)l2 * 2u;

    const int beg = __builtin_amdgcn_readfirstlane(offs[node]);
    const int d   = __builtin_amdgcn_readfirstlane(deg[node]);

    float m = -3.0e38f, den = 0.f;
    f16x2 a01 = (f16x2){(f16)0.f, (f16)0.f};

    auto loadE = [&](int i, float& sbf, unsigned& kc, unsigned& vc) {
        if (i < d) {
            const int2 e = ed[beg + i];
            sbf = __int_as_float(e.y);
            const unsigned b = (unsigned)e.x * 512u + lb;
            kc = *(const unsigned*)(KV + b);
            vc = *(const unsigned*)(KV + b + 256);
        } else {
            sbf = __int_as_float((int)0xFF800000u);   // -inf -> zero contribution
            kc = 0; vc = 0;
        }
    };

    auto procPair = [&](float sf0, unsigned k0, unsigned v0,
                        float sf1, unsigned k1, unsigned v1) {
        float sa = head_sum(hdot(qp, u2h(k0))) + sf0;
        float sb = head_sum(hdot(qp, u2h(k1))) + sf1;
        const float pm = fmaxf(sa, sb);
        if (!__all(pm <= m + 8.f)) {           // defer-max
            const float mn = fmaxf(m, pm);
            const float sc = exp2f(m - mn);
            den *= sc;
            a01 *= u2h(pk2(sc, sc));
            m = mn;
        }
        const float ea = exp2f(sa - m);
        const float eb = exp2f(sb - m);
        den += ea + eb;
        a01 += u2h(pk2(ea, ea)) * u2h(v0);
        a01 += u2h(pk2(eb, eb)) * u2h(v1);
    };

    float sA0, sA1, sA2, sA3, sB0, sB1, sB2, sB3;
    unsigned kA0, kA1, kA2, kA3, kB0, kB1, kB2, kB3;
    unsigned vA0, vA1, vA2, vA3, vB0, vB1, vB2, vB3;
    loadE(0, sA0, kA0, vA0); loadE(1, sA1, kA1, vA1);
    loadE(2, sA2, kA2, vA2); loadE(3, sA3, kA3, vA3);
    loadE(4, sB0, kB0, vB0); loadE(5, sB1, kB1, vB1);
    loadE(6, sB2, kB2, vB2); loadE(7, sB3, kB3, vB3);

    for (int i = 0; i < d; i += 8) {
        procPair(sA0, kA0, vA0, sA1, kA1, vA1);
        procPair(sA2, kA2, vA2, sA3, kA3, vA3);
        loadE(i + 8,  sA0, kA0, vA0); loadE(i + 9,  sA1, kA1, vA1);
        loadE(i + 10, sA2, kA2, vA2); loadE(i + 11, sA3, kA3, vA3);
        procPair(sB0, kB0, vB0, sB1, kB1, vB1);
        procPair(sB2, kB2, vB2, sB3, kB3, vB3);
        loadE(i + 12, sB0, kB0, vB0); loadE(i + 13, sB1, kB1, vB1);
        loadE(i + 14, sB2, kB2, vB2); loadE(i + 15, sB3, kB3, vB3);
    }

    const float inv = (den > 0.f) ? 1.f / den : 0.f;   // empty segment -> message 0
    const float2 xv = *(const float2*)(x + (size_t)node * CH + l2);
    const float w0 = (float)a01[0] * inv + xv.x;
    const float w1 = (float)a01[1] * inv + xv.y;

    float sum = w0 + w1;
    #pragma unroll
    for (int off = 32; off; off >>= 1) sum += __shfl_xor(sum, off);
    const float mean = sum * (1.f / 128.f);
    const float c0 = w0 - mean, c1 = w1 - mean;
    float vs = c0 * c0 + c1 * c1;
    #pragma unroll
    for (int off = 32; off; off >>= 1) vs += __shfl_xor(vs, off);
    const float rstd = rsqrtf(vs * (1.f / 128.f) + 1e-5f);

    const float2 g = *(const float2*)(gamma + l2);
    const float2 bt = *(const float2*)(beta + l2);
    float2 ov;
    ov.x = c0 * rstd * g.x + bt.x;
    ov.y = c1 * rstd * g.y + bt.y;
    *(float2*)(o + (size_t)node * CH + l2) = ov;
}

extern "C" void kernel_launch(void* const* d_in, const int* in_sizes, int n_in,
                              void* d_out, int out_size, void* d_ws, size_t ws_size,
                              hipStream_t stream)
{
    const float* xA     = (const float*)d_in[0];
    const float* xB     = (const float*)d_in[1];
    const float* Wq     = (const float*)d_in[2];
    const float* bq     = (const float*)d_in[3];
    const float* Wk     = (const float*)d_in[4];
    const float* bk     = (const float*)d_in[5];
    const float* Wv     = (const float*)d_in[6];
    const float* bv     = (const float*)d_in[7];
    const float* gamma  = (const float*)d_in[8];
    const float* beta   = (const float*)d_in[9];
    const float* biasAB = (const float*)d_in[10];
    const float* biasBA = (const float*)d_in[11];
    const float* sbAB   = (const float*)d_in[12];
    const float* sbBA   = (const float*)d_in[13];
    const int*   eiAB   = (const int*)d_in[14];
    const int*   eiBA   = (const int*)d_in[15];

    const int n  = in_sizes[0] / CH;     // 100000
    const int nE = in_sizes[12];         // 1000000
    const size_t NC = (size_t)n * CH;

    // ---- workspace carve-up (16B aligned) ----
    char* p = (char*)d_ws;
    auto carve = [&](size_t bytes) { char* r = p; p += (bytes + 15) & ~(size_t)15; return r; };
    unsigned short* Qb  = (unsigned short*)carve(2 * NC * 2);              // [2][n][128] f16
    unsigned short* KVb = (unsigned short*)carve((size_t)2 * n * 256 * 2); // [2][n][256] f16
    unsigned short* Wb  = (unsigned short*)carve(3 * CH * CH * 2);
    int2* edAB  = (int2*)carve((size_t)nE * 8);
    int2* edBA  = (int2*)carve((size_t)nE * 8);
    int* offsAB = (int*)carve((size_t)n * 4);
    int* offsBA = (int*)carve((size_t)n * 4);
    int* degAB  = (int*)carve((size_t)2 * n * 4);   // degAB,degBA contiguous (one memset)
    int* degBA  = degAB + n;
    int* curAB  = (int*)carve((size_t)n * 4);
    int* curBA  = (int*)carve((size_t)n * 4);
    int* bsums  = (int*)carve(2 * 256 * 4);

    float* out = (float*)d_out;

    (void)hipMemsetAsync(degAB, 0, (size_t)2 * n * sizeof(int), stream);

    wcvt<<<(3 * CH * CH + 255) / 256, 256, 0, stream>>>(Wq, Wk, Wv, Wb);

    dim3 qkv_grid((n + 63) / 64, 2);
    qkv_mfma<<<qkv_grid, 256, 0, stream>>>(xA, xB, Wb, bq, bk, bv, Qb, KVb, n);

    const int ebl4 = (nE + 1023) / 1024;
    deg_hist<<<2 * ebl4, 256, 0, stream>>>(eiAB, eiBA, degAB, degBA, nE, ebl4);

    const int nb = (n + SCAN_BLK - 1) / SCAN_BLK;   // 98 <= 256
    scan_local<<<2 * nb, 256, 0, stream>>>(degAB, degBA, offsAB, offsBA, bsums, n, nb);
    scan_bsums<<<2, 256, 0, stream>>>(bsums, nb);
    const int nbl = (n + 255) / 256;
    add_bsums<<<2 * nbl, 256, 0, stream>>>(offsAB, offsBA, curAB, curBA, bsums, n, nbl);

    csr_fill<<<2 * ebl4, 256, 0, stream>>>(eiAB, eiBA, sbAB, sbBA, biasAB, biasBA,
                                           curAB, curBA, edAB, edBA, nE, ebl4);

    const int abl = (n + 3) / 4;
    attn_node<<<2 * abl, 256, 0, stream>>>(Qb, KVb, xA, xB, offsAB, offsBA, degAB, degBA,
                                           edAB, edBA, gamma, beta, out, n, abl);
}